// Round 4
// baseline (982.202 us; speedup 1.0000x reference)
//
#include <hip/hip_runtime.h>
#include <stdint.h>

#define BB 8
#define TT 4096
#define DIN 1024
#define DC 256
#define CS 8192
#define EPSF 1e-12f

typedef unsigned short ushort_t;
typedef __attribute__((ext_vector_type(8))) short short8;
typedef __attribute__((ext_vector_type(4))) float f32x4;

// ---------------- workspace layout (bytes) ----------------
constexpr size_t OFF_WIN   = 0;                          // w_in fp32: 1MB
constexpr size_t OFF_WOUTT = OFF_WIN   + 1048576;        // w_outT fp32: 1MB (fallback only)
constexpr size_t OFF_CBN   = OFF_WOUTT + 1048576;        // cb_hi/cb_lo bf16: 8.39MB
constexpr size_t OFF_NRM2  = OFF_CBN   + 8388608;        // nrm2: 32KB
constexpr size_t OFF_ZE    = OFF_NRM2  + 32768;          // z_e fp32: 33.55MB
constexpr size_t OFF_INV   = OFF_ZE    + 33554432;       // inv: 128KB
constexpr size_t OFF_ENC2  = OFF_INV   + 131072;         // enc2: 128KB
constexpr size_t OFF_KEYS  = OFF_ENC2  + 131072;         // keys u64: 256KB
constexpr size_t OFF_LOSS  = OFF_KEYS  + 262144;         // loss: 256B
constexpr size_t OFF_WSPL  = OFF_LOSS  + 256;            // w_hi/w_lo bf16: 1MB
constexpr size_t OFF_W2T   = OFF_WSPL  + 1048576;        // zT(134MB) -> enc(67MB) -> W2T(33.6MB)+cbr/wout splits
constexpr size_t REQ_WS_ZE = OFF_W2T + 134217728ull;     // ~180MB: needed for MFMA z_e path

// ---------------- helpers ----------------
__device__ __forceinline__ float block_reduce_sum_256(float v, float* sbuf) {
  #pragma unroll
  for (int o = 32; o > 0; o >>= 1) v += __shfl_down(v, o, 64);
  int lane = threadIdx.x & 63, w = threadIdx.x >> 6;
  if (lane == 0) sbuf[w] = v;
  __syncthreads();
  float r = sbuf[0] + sbuf[1] + sbuf[2] + sbuf[3];
  __syncthreads();
  return r;
}

__device__ __forceinline__ ushort_t bf16_rne(float x) {
  unsigned u = __float_as_uint(x);
  unsigned r = (u + 0x7FFFu + ((u >> 16) & 1u)) >> 16;
  return (ushort_t)r;
}
__device__ __forceinline__ float bf16f(ushort_t h) {
  return __uint_as_float(((unsigned)h) << 16);
}

// LDS chunk swizzle (proven config: conflict-free fragment reads under the
// 8-lane/cycle model; 2.5e7 residual conflicts measured in this kernel shape).
__device__ __forceinline__ int swz4(int r) {
  return (r + (r >> 2)) & 3;
}

__device__ __forceinline__ void async_copy16(const ushort_t* g, ushort_t* lds) {
  __builtin_amdgcn_global_load_lds(
      (const __attribute__((address_space(1))) void*)g,
      (__attribute__((address_space(3))) void*)lds, 16, 0, 0);
}

// stage one 128x32 bf16 tile (8KB) into LDS; per-wave; offsets precomputed.
// go[i] = per-lane element offset (r*ld + g*8) for row-group i, k-invariant.
__device__ __forceinline__ void stage_tile8(const ushort_t* __restrict__ s0,
                                            ushort_t* __restrict__ dstbuf,
                                            const int (&go)[8]) {
  #pragma unroll
  for (int i = 0; i < 8; i++) async_copy16(s0 + go[i], dstbuf + i*512);
}

// stage one 128x32 bf16 comp tile (8KB) into LDS; 256 threads, 2 loads each;
// per-lane global offsets precomputed (k-invariant).
__device__ __forceinline__ void stageD(const ushort_t* __restrict__ srcbase,
                                       ushort_t* __restrict__ comp,
                                       const int (&go)[2], int wu) {
  async_copy16(srcbase + go[0], comp + wu);
  async_copy16(srcbase + go[1], comp + wu + 2048);
}

#define LD8(base, off) (*(const short8*)((const char*)(base) + (off)))

// ---------------- weight prep ----------------
__global__ void k_prep_win(const float* __restrict__ v, const float* __restrict__ g,
                           float* __restrict__ w, ushort_t* __restrict__ wh,
                           ushort_t* __restrict__ wl) {
  __shared__ float sb[4];
  int r = blockIdx.x, t = threadIdx.x;
  float xv[4]; float s = 0.f;
  #pragma unroll
  for (int i = 0; i < 4; i++) { xv[i] = v[r*DIN + t + i*256]; s += xv[i]*xv[i]; }
  s = block_reduce_sum_256(s, sb);
  float sc = g[r] / fmaxf(sqrtf(s), EPSF);
  #pragma unroll
  for (int i = 0; i < 4; i++) {
    float val = xv[i] * sc;
    int idx = r*DIN + t + i*256;
    w[idx] = val;
    ushort_t h = bf16_rne(val);
    wh[idx] = h;
    wl[idx] = bf16_rne(val - bf16f(h));
  }
}

__global__ void k_prep_wout(const float* __restrict__ v, const float* __restrict__ g,
                            float* __restrict__ wT) {
  __shared__ float sb[4];
  int r = blockIdx.x, t = threadIdx.x;
  float x = v[r*DC + t];
  float s = block_reduce_sum_256(x*x, sb);
  float sc = g[r] / fmaxf(sqrtf(s), EPSF);
  wT[t*DIN + r] = x * sc;
}

__global__ void k_prep_cb(const float* __restrict__ cb, ushort_t* __restrict__ cbh,
                          ushort_t* __restrict__ cbl, float* __restrict__ nrm2) {
  __shared__ float sb[4];
  int j = blockIdx.x, t = threadIdx.x;
  float x = cb[j*DC + t];
  float s = block_reduce_sum_256(x*x, sb);
  float nm = fmaxf(sqrtf(s), EPSF);
  float cn = x / nm;
  ushort_t h = bf16_rne(cn);
  cbh[j*DC + t] = h;
  cbl[j*DC + t] = bf16_rne(cn - bf16f(h));
  float q = block_reduce_sum_256(cn*cn, sb);
  if (t == 0) nrm2[j] = q;
}

// raw codebook bf16 split (for W2T MFMA GEMM); runs after dist into freed region
__global__ void k_split_cbraw(const float* __restrict__ cb, ushort_t* __restrict__ ch,
                              ushort_t* __restrict__ cl) {
  int j = blockIdx.x, t = threadIdx.x;
  float x = cb[j*DC + t];
  ushort_t h = bf16_rne(x);
  ch[j*DC + t] = h;
  cl[j*DC + t] = bf16_rne(x - bf16f(h));
}

// weight-normed out_v, row-major [DIN][DC], bf16 split
__global__ void k_split_wout(const float* __restrict__ v, const float* __restrict__ g,
                             ushort_t* __restrict__ wh, ushort_t* __restrict__ wl) {
  __shared__ float sb[4];
  int r = blockIdx.x, t = threadIdx.x;
  float x = v[r*DC + t];
  float s = block_reduce_sum_256(x*x, sb);
  float sc = g[r] / fmaxf(sqrtf(s), EPSF);
  float val = x * sc;
  ushort_t h = bf16_rne(val);
  wh[r*DC + t] = h;
  wl[r*DC + t] = bf16_rne(val - bf16f(h));
}

// ---------------- fp32 GEMM (fallback path only) ----------------
template<bool BIAS>
__global__ __launch_bounds__(256) void k_gemm(
    const float* __restrict__ A, const float* __restrict__ Bmat,
    const float* __restrict__ bias, float* __restrict__ C,
    int K, int lda, int ldb, int ldc, size_t strideB, size_t strideC)
{
  __shared__ float As[16][132];
  __shared__ float Bs[16][132];
  const int bn = blockIdx.x * 128;
  const int bm = blockIdx.y * 128;
  const float* Bb = Bmat + (size_t)blockIdx.z * strideB;
  float* Cb = C + (size_t)blockIdx.z * strideC;
  const int tid = threadIdx.x;
  const int tx = tid & 15, ty = tid >> 4;
  const int am = tid & 127, akq = (tid >> 7) * 8;
  const int bk = tid >> 5, bj = (tid & 31) * 4;

  float acc[8][8];
  #pragma unroll
  for (int i = 0; i < 8; i++)
    #pragma unroll
    for (int j = 0; j < 8; j++) acc[i][j] = 0.f;

  for (int k0 = 0; k0 < K; k0 += 16) {
    float4 a0 = *(const float4*)&A[(size_t)(bm+am)*lda + k0 + akq];
    float4 a1 = *(const float4*)&A[(size_t)(bm+am)*lda + k0 + akq + 4];
    float4 b0 = *(const float4*)&Bb[(size_t)(k0+bk)*ldb + bn + bj];
    float4 b1 = *(const float4*)&Bb[(size_t)(k0+bk+8)*ldb + bn + bj];
    As[akq+0][am] = a0.x; As[akq+1][am] = a0.y; As[akq+2][am] = a0.z; As[akq+3][am] = a0.w;
    As[akq+4][am] = a1.x; As[akq+5][am] = a1.y; As[akq+6][am] = a1.z; As[akq+7][am] = a1.w;
    *(float4*)&Bs[bk][bj] = b0;
    *(float4*)&Bs[bk+8][bj] = b1;
    __syncthreads();
    #pragma unroll
    for (int k = 0; k < 16; k++) {
      float av[8], bv[8];
      float4 x0 = *(const float4*)&As[k][tx*4];
      float4 x1 = *(const float4*)&As[k][tx*4+64];
      float4 y0 = *(const float4*)&Bs[k][ty*4];
      float4 y1 = *(const float4*)&Bs[k][ty*4+64];
      av[0]=x0.x; av[1]=x0.y; av[2]=x0.z; av[3]=x0.w;
      av[4]=x1.x; av[5]=x1.y; av[6]=x1.z; av[7]=x1.w;
      bv[0]=y0.x; bv[1]=y0.y; bv[2]=y0.z; bv[3]=y0.w;
      bv[4]=y1.x; bv[5]=y1.y; bv[6]=y1.z; bv[7]=y1.w;
      #pragma unroll
      for (int i = 0; i < 8; i++)
        #pragma unroll
        for (int j = 0; j < 8; j++)
          acc[i][j] += av[i] * bv[j];
    }
    __syncthreads();
  }

  #pragma unroll
  for (int i = 0; i < 8; i++) {
    int mm = bm + ((i < 4) ? tx*4 + i : 64 + tx*4 + (i-4));
    float bia = BIAS ? bias[mm] : 0.f;
    float4 v0 = make_float4(acc[i][0]+bia, acc[i][1]+bia, acc[i][2]+bia, acc[i][3]+bia);
    float4 v1 = make_float4(acc[i][4]+bia, acc[i][5]+bia, acc[i][6]+bia, acc[i][7]+bia);
    *(float4*)&Cb[(size_t)mm*ldc + bn + ty*4]      = v0;
    *(float4*)&Cb[(size_t)mm*ldc + bn + 64 + ty*4] = v1;
  }
}

// ---------------- split z: [b][d][t] -> zT hi/lo [b][t][d] ----------------
__global__ void k_split_z(const float* __restrict__ z, ushort_t* __restrict__ zhi,
                          ushort_t* __restrict__ zlo) {
  __shared__ float tile[64][65];
  int b = blockIdx.z, t0 = blockIdx.x * 64, d0 = blockIdx.y * 64;
  int tx = threadIdx.x & 63, ty = threadIdx.x >> 6;
  const float* zb = z + (size_t)b*DIN*TT;
  #pragma unroll
  for (int i = 0; i < 16; i++) {
    int d = i*4 + ty;
    tile[d][tx] = zb[(size_t)(d0+d)*TT + t0 + tx];
  }
  __syncthreads();
  #pragma unroll
  for (int i = 0; i < 16; i++) {
    int t = i*4 + ty;
    float val = tile[tx][t];                 // z[d0+tx][t0+t]
    ushort_t h = bf16_rne(val);
    size_t o = ((size_t)(b*TT + t0 + t))*DIN + d0 + tx;
    zhi[o] = h;
    zlo[o] = bf16_rne(val - bf16f(h));
  }
}

// ---------------- z_e via split-bf16 MFMA, double-buffered ----------------
// grid: (TT/128, DC/128, B); out z_e[b][c][t] fp32, K=DIN=1024
__global__ __launch_bounds__(256) void k_ze_mfma(
    const ushort_t* __restrict__ zth, const ushort_t* __restrict__ ztl,
    const ushort_t* __restrict__ wh, const ushort_t* __restrict__ wl,
    const float* __restrict__ in_b, float* __restrict__ ze)
{
  __shared__ ushort_t As_hi[2][4096];
  __shared__ ushort_t As_lo[2][4096];
  __shared__ ushort_t Bs_hi[2][4096];
  __shared__ ushort_t Bs_lo[2][4096];

  const int b  = blockIdx.z;
  const int t0 = blockIdx.x * 128;
  const int c0 = blockIdx.y * 128;
  const int tid = threadIdx.x;
  const int lane = tid & 63;
  const int wave = tid >> 6;
  const int wr = wave >> 1, wc = wave & 1;
  const int m = lane & 15, quad = lane >> 4;

  const ushort_t* src; ushort_t* dst;
  {
    size_t aoff = ((size_t)(b*TT + t0)) * DIN;
    size_t boff = (size_t)c0 * DIN;
    if      (wave == 0) { src = zth + aoff; dst = &As_hi[0][0]; }
    else if (wave == 1) { src = ztl + aoff; dst = &As_lo[0][0]; }
    else if (wave == 2) { src = wh + boff;  dst = &Bs_hi[0][0]; }
    else                { src = wl + boff;  dst = &Bs_lo[0][0]; }
  }
  const int rr = lane >> 2, cc = lane & 3;

  // per-lane staging offsets, k-invariant
  int goT[8];
  #pragma unroll
  for (int i = 0; i < 8; i++) {
    int r = i*16 + rr;
    int g = cc ^ swz4(r);
    goT[i] = r*DIN + (g << 3);
  }

  int offA[4], offB[4];
  #pragma unroll
  for (int ri = 0; ri < 4; ri++) {
    int r = wr*64 + ri*16 + m;
    int p = quad ^ swz4(r);
    offA[ri] = r*64 + p*16;
  }
  #pragma unroll
  for (int ci = 0; ci < 4; ci++) {
    int r = wc*64 + ci*16 + m;
    int p = quad ^ swz4(r);
    offB[ci] = r*64 + p*16;
  }

  f32x4 acc[4][4];
  #pragma unroll
  for (int i = 0; i < 4; i++)
    #pragma unroll
    for (int j = 0; j < 4; j++) acc[i][j] = (f32x4)0.f;

  stage_tile8(src, dst, goT);

  for (int it = 0; it < 32; ++it) {
    __syncthreads();                           // drains stage(it) (issued 1 iter ago)
    if (it < 31) stage_tile8(src + (it+1)*32, dst + ((it+1)&1)*4096, goT);
    const int bo = (it & 1) << 13;             // byte offset of current buffer

    short8 bh[4], bl[4];
    #pragma unroll
    for (int ci = 0; ci < 4; ci++) {
      bh[ci] = *(const short8*)((const char*)Bs_hi + bo + offB[ci]);
      bl[ci] = *(const short8*)((const char*)Bs_lo + bo + offB[ci]);
    }
    #pragma unroll
    for (int ri = 0; ri < 4; ri++) {
      short8 ah = *(const short8*)((const char*)As_hi + bo + offA[ri]);
      short8 al = *(const short8*)((const char*)As_lo + bo + offA[ri]);
      #pragma unroll
      for (int ci = 0; ci < 4; ci++) {
        acc[ri][ci] = __builtin_amdgcn_mfma_f32_16x16x32_bf16(ah, bh[ci], acc[ri][ci], 0, 0, 0);
        acc[ri][ci] = __builtin_amdgcn_mfma_f32_16x16x32_bf16(al, bh[ci], acc[ri][ci], 0, 0, 0);
        acc[ri][ci] = __builtin_amdgcn_mfma_f32_16x16x32_bf16(ah, bl[ci], acc[ri][ci], 0, 0, 0);
      }
    }
  }

  // store: C[m=t][n=c] -> z_e[b][c0+c][t0+t] (+bias), 4 consecutive t per lane
  #pragma unroll
  for (int ri = 0; ri < 4; ri++) {
    int t_loc = wr*64 + ri*16 + quad*4;
    #pragma unroll
    for (int ci = 0; ci < 4; ci++) {
      int c_loc = wc*64 + ci*16 + m;
      float bia = in_b[c0 + c_loc];
      float4 v = make_float4(acc[ri][ci][0]+bia, acc[ri][ci][1]+bia,
                             acc[ri][ci][2]+bia, acc[ri][ci][3]+bia);
      *(float4*)&ze[((size_t)b*DC + c0 + c_loc)*TT + t0 + t_loc] = v;
    }
  }
}

// ---------------- W2T via split-bf16 MFMA ----------------
// W2T[j][d] = sum_c codebook[j][c] * w_out[d][c]; A=cbr (8192xK256), B=wout (1024xK256)
// grid: (8192/128, 1024/128); C row-major [8192][1024] fp32
__global__ __launch_bounds__(256) void k_w2t_mfma(
    const ushort_t* __restrict__ ah_g, const ushort_t* __restrict__ al_g,
    const ushort_t* __restrict__ bh_g, const ushort_t* __restrict__ bl_g,
    float* __restrict__ C)
{
  __shared__ ushort_t As_hi[2][4096];
  __shared__ ushort_t As_lo[2][4096];
  __shared__ ushort_t Bs_hi[2][4096];
  __shared__ ushort_t Bs_lo[2][4096];

  const int m0 = blockIdx.x * 128;
  const int n0 = blockIdx.y * 128;
  const int tid = threadIdx.x;
  const int lane = tid & 63;
  const int wave = tid >> 6;
  const int wr = wave >> 1, wc = wave & 1;
  const int m = lane & 15, quad = lane >> 4;

  const ushort_t* src; ushort_t* dst;
  {
    size_t aoff = (size_t)m0 * DC;
    size_t boff = (size_t)n0 * DC;
    if      (wave == 0) { src = ah_g + aoff; dst = &As_hi[0][0]; }
    else if (wave == 1) { src = al_g + aoff; dst = &As_lo[0][0]; }
    else if (wave == 2) { src = bh_g + boff; dst = &Bs_hi[0][0]; }
    else                { src = bl_g + boff; dst = &Bs_lo[0][0]; }
  }
  const int rr = lane >> 2, cc = lane & 3;

  int goT[8];
  #pragma unroll
  for (int i = 0; i < 8; i++) {
    int r = i*16 + rr;
    int g = cc ^ swz4(r);
    goT[i] = r*DC + (g << 3);
  }

  int offA[4], offB[4];
  #pragma unroll
  for (int ri = 0; ri < 4; ri++) {
    int r = wr*64 + ri*16 + m;
    int p = quad ^ swz4(r);
    offA[ri] = r*64 + p*16;
  }
  #pragma unroll
  for (int ci = 0; ci < 4; ci++) {
    int r = wc*64 + ci*16 + m;
    int p = quad ^ swz4(r);
    offB[ci] = r*64 + p*16;
  }

  f32x4 acc[4][4];
  #pragma unroll
  for (int i = 0; i < 4; i++)
    #pragma unroll
    for (int j = 0; j < 4; j++) acc[i][j] = (f32x4)0.f;

  stage_tile8(src, dst, goT);

  for (int it = 0; it < 8; ++it) {
    __syncthreads();
    if (it < 7) stage_tile8(src + (it+1)*32, dst + ((it+1)&1)*4096, goT);
    const int bo = (it & 1) << 13;

    short8 bh[4], bl[4];
    #pragma unroll
    for (int ci = 0; ci < 4; ci++) {
      bh[ci] = *(const short8*)((const char*)Bs_hi + bo + offB[ci]);
      bl[ci] = *(const short8*)((const char*)Bs_lo + bo + offB[ci]);
    }
    #pragma unroll
    for (int ri = 0; ri < 4; ri++) {
      short8 ah = *(const short8*)((const char*)As_hi + bo + offA[ri]);
      short8 al = *(const short8*)((const char*)As_lo + bo + offA[ri]);
      #pragma unroll
      for (int ci = 0; ci < 4; ci++) {
        acc[ri][ci] = __builtin_amdgcn_mfma_f32_16x16x32_bf16(ah, bh[ci], acc[ri][ci], 0, 0, 0);
        acc[ri][ci] = __builtin_amdgcn_mfma_f32_16x16x32_bf16(al, bh[ci], acc[ri][ci], 0, 0, 0);
        acc[ri][ci] = __builtin_amdgcn_mfma_f32_16x16x32_bf16(ah, bl[ci], acc[ri][ci], 0, 0, 0);
      }
    }
  }

  // store: C[m0+m_loc][n0+n_loc], m = A-row (j), n = B-row (d)
  #pragma unroll
  for (int ri = 0; ri < 4; ri++) {
    int m_loc = wr*64 + ri*16 + quad*4;
    #pragma unroll
    for (int ci = 0; ci < 4; ci++) {
      int n_loc = wc*64 + ci*16 + m;
      #pragma unroll
      for (int reg = 0; reg < 4; reg++) {
        C[(size_t)(m0 + m_loc + reg)*DIN + n0 + n_loc] = acc[ri][ci][reg];
      }
    }
  }
}

// ---------------- column norms of z_e ----------------
__global__ void k_colnorm(const float* __restrict__ ze, float* __restrict__ inv,
                          float* __restrict__ enc2) {
  int r = blockIdx.x * 128 + threadIdx.x;
  int b = r >> 12, t = r & 4095;
  const float* p = ze + (size_t)b*DC*TT + t;
  float s = 0.f;
  for (int c = 0; c < DC; c++) { float x = p[(size_t)c*TT]; s += x*x; }
  float iv = 1.f / fmaxf(sqrtf(s), EPSF);
  inv[r] = iv;
  enc2[r] = (s * iv) * iv;
}

// ---------------- normalize + transpose + bf16-split enc ----------------
__global__ void k_split_enc(const float* __restrict__ ze, const float* __restrict__ inv,
                            ushort_t* __restrict__ ehi, ushort_t* __restrict__ elo) {
  __shared__ float tile[64][65];
  int b = blockIdx.z, t0 = blockIdx.x * 64, c0 = blockIdx.y * 64;
  int tx = threadIdx.x & 63, ty = threadIdx.x >> 6;
  const float* zb = ze + (size_t)b*DC*TT;
  #pragma unroll
  for (int i = 0; i < 16; i++) {
    int c = i*4 + ty;
    tile[c][tx] = zb[(size_t)(c0+c)*TT + t0 + tx];
  }
  __syncthreads();
  #pragma unroll
  for (int i = 0; i < 16; i++) {
    int t = i*4 + ty;
    float iv = inv[b*TT + t0 + t];
    float val = tile[tx][t] * iv;
    ushort_t h = bf16_rne(val);
    size_t o = ((size_t)(b*TT + t0 + t))*DC + c0 + tx;
    ehi[o] = h;
    elo[o] = bf16_rne(val - bf16f(h));
  }
}

// ---------------- fused distance + argmin ----------------
// 128x128 tile, 4 waves (2x2), 64KB LDS -> 2 blocks/CU. The co-resident block
// provides the LDS-read/MFMA overlap the lockstep barrier schedule cannot:
// while one block is in its read/stage window the other feeds the MFMA pipe.
// Simple 1-barrier-per-K-step loop (m97 style): stage(k+1) issued at top of
// iter k (HBM latency hidden under this iter's reads+MFMA), __syncthreads at
// the bottom drains it (vmcnt(0)) and publishes the buffer.
// Per wave: 64(t) x 64(j), acc[4][4]; 16 ds_read_b128 : 48 MFMA per K-step.
// Accumulation order per output element (hh/lh/hl, ascending K=32 chunks) is
// IDENTICAL to all prior passing kernels -> bitwise-identical distances.
__global__ __launch_bounds__(256, 2) void k_dist_mfma(
    const ushort_t* __restrict__ ehi, const ushort_t* __restrict__ elo,
    const ushort_t* __restrict__ cbh, const ushort_t* __restrict__ cbl,
    const float* __restrict__ nrm2, const float* __restrict__ enc2,
    unsigned long long* __restrict__ keys)
{
  __shared__ ushort_t sAh[2][4096];
  __shared__ ushort_t sAl[2][4096];
  __shared__ ushort_t sBh[2][4096];
  __shared__ ushort_t sBl[2][4096];
  __shared__ float sE2[128], sN2[128];
  __shared__ unsigned long long rkey[128];

  const int j0 = blockIdx.x * 128;
  const size_t r0 = (size_t)blockIdx.y * 128;     // global bt-row base
  const int tid = threadIdx.x;
  const int lane = tid & 63;
  const int wave = tid >> 6;
  const int wr = wave >> 1, wc = wave & 1;        // 2x2 wave grid
  const int ml = lane & 15, quad = lane >> 4;

  if (tid < 128) {
    sE2[tid] = enc2[r0 + tid];
    sN2[tid] = nrm2[j0 + tid];
    rkey[tid] = 0xFFFFFFFFFFFFFFFFull;
  }

  const ushort_t* gAh = ehi + r0 * DC;
  const ushort_t* gAl = elo + r0 * DC;
  const ushort_t* gBh = cbh + (size_t)j0 * DC;
  const ushort_t* gBl = cbl + (size_t)j0 * DC;

  // per-lane staging offsets (element units), k-invariant. 512 chunks of 16B
  // per 128x32 tile; thread handles chunks tid and tid+256.
  int goS[2];
  #pragma unroll
  for (int l = 0; l < 2; l++) {
    int chunk = l*256 + tid;
    int r = chunk >> 2, c = chunk & 3;
    int g = c ^ swz4(r);
    goS[l] = r*DC + (g << 3);
  }
  const int wu = wave * 512;   // wave-uniform LDS dest offset (elements)

  int offA[4], offB[4];
  #pragma unroll
  for (int i = 0; i < 4; i++) {
    int r = wr*64 + i*16 + ml;
    int p = quad ^ swz4(r);
    offA[i] = r*64 + p*16;
  }
  #pragma unroll
  for (int i = 0; i < 4; i++) {
    int r = wc*64 + i*16 + ml;
    int p = quad ^ swz4(r);
    offB[i] = r*64 + p*16;
  }

  f32x4 acc[4][4];
  #pragma unroll
  for (int i = 0; i < 4; i++)
    #pragma unroll
    for (int j = 0; j < 4; j++) acc[i][j] = (f32x4)0.f;

  stageD(gAh, &sAh[0][0], goS, wu);
  stageD(gAl, &sAl[0][0], goS, wu);
  stageD(gBh, &sBh[0][0], goS, wu);
  stageD(gBl, &sBl[0][0], goS, wu);
  __syncthreads();                               // stage(0) drained + sE2/sN2/rkey

  #pragma unroll 2
  for (int k = 0; k < 8; ++k) {
    const int cb = k & 1, nb = cb ^ 1;
    // issue next tile first: HBM latency hides under this iter's reads+MFMA.
    // buf[nb] was fully consumed in iter k-1 (reads completed before its
    // waves' barrier arrival), so the write is race-free.
    if (k < 7) {
      stageD(gAh + (size_t)(k+1)*32, &sAh[nb][0], goS, wu);
      stageD(gAl + (size_t)(k+1)*32, &sAl[nb][0], goS, wu);
      stageD(gBh + (size_t)(k+1)*32, &sBh[nb][0], goS, wu);
      stageD(gBl + (size_t)(k+1)*32, &sBl[nb][0], goS, wu);
    }
    const char* pAh = (const char*)&sAh[cb][0];
    const char* pAl = (const char*)&sAl[cb][0];
    const char* pBh = (const char*)&sBh[cb][0];
    const char* pBl = (const char*)&sBl[cb][0];

    short8 fah[4], fal[4], fbh[4], fbl[4];
    #pragma unroll
    for (int i = 0; i < 4; i++) {
      fah[i] = LD8(pAh, offA[i]); fal[i] = LD8(pAl, offA[i]);
      fbh[i] = LD8(pBh, offB[i]); fbl[i] = LD8(pBl, offB[i]);
    }
    __builtin_amdgcn_s_setprio(1);
    #pragma unroll
    for (int ri = 0; ri < 4; ri++) {
      #pragma unroll
      for (int ci = 0; ci < 4; ci++) {
        f32x4 t = acc[ri][ci];
        t = __builtin_amdgcn_mfma_f32_16x16x32_bf16(fah[ri], fbh[ci], t, 0, 0, 0);
        t = __builtin_amdgcn_mfma_f32_16x16x32_bf16(fal[ri], fbh[ci], t, 0, 0, 0);
        t = __builtin_amdgcn_mfma_f32_16x16x32_bf16(fah[ri], fbl[ci], t, 0, 0, 0);
        acc[ri][ci] = t;
      }
    }
    __builtin_amdgcn_s_setprio(0);
    __syncthreads();                             // drains stage(k+1), publishes buf[nb]
  }

  // ---- epilogue: dist = e2 - 2*dot + n2; per-row argmin ----
  #pragma unroll
  for (int ri = 0; ri < 4; ri++) {
    #pragma unroll
    for (int reg = 0; reg < 4; reg++) {
      int t_loc = wr*64 + ri*16 + quad*4 + reg;
      float e2 = sE2[t_loc];
      unsigned long long best = 0xFFFFFFFFFFFFFFFFull;
      #pragma unroll
      for (int ci = 0; ci < 4; ci++) {
        int j_loc = wc*64 + ci*16 + ml;
        float d = e2 - 2.0f * acc[ri][ci][reg];
        d = d + sN2[j_loc];
        unsigned long long key =
            ((unsigned long long)__float_as_uint(d) << 32) | (unsigned)(j0 + j_loc);
        best = key < best ? key : best;
      }
      #pragma unroll
      for (int off = 1; off < 16; off <<= 1) {
        unsigned long long o = __shfl_xor(best, off);
        best = o < best ? o : best;
      }
      if (ml == 0) atomicMin(&rkey[t_loc], best);
    }
  }
  __syncthreads();
  if (tid < 128) atomicMin(&keys[r0 + tid], rkey[tid]);
}

// ---------------- losses + indices ----------------
__global__ void k_lossidx(const float* __restrict__ ze, const float* __restrict__ cb,
                          const unsigned long long* __restrict__ keys,
                          float* __restrict__ loss_sums, float* __restrict__ out_idx)
{
  __shared__ float sb[4];
  __shared__ int sj[64];
  int b = blockIdx.y, t0 = blockIdx.x * 64;
  int tid = threadIdx.x;
  if (tid < 64) {
    unsigned long long k = keys[(size_t)b*TT + t0 + tid];
    int j = (int)(unsigned)(k & 0xFFFFFFFFull);
    sj[tid] = j;
    out_idx[(size_t)b*TT + t0 + tid] = (float)j;
  }
  __syncthreads();
  int tt = tid & 63, tc = tid >> 6;
  const float* zb = ze + (size_t)b*DC*TT + t0;
  int j = sj[tt];
  float s = 0.f;
  for (int ci = 0; ci < 64; ci++) {
    int c = tc + ci*4;
    float zev = zb[(size_t)c*TT + tt];
    float zqv = cb[(size_t)j*DC + c];
    float d = zev - zqv;
    s += d*d;
  }
  s = block_reduce_sum_256(s, sb);
  if (tid == 0) atomicAdd(&loss_sums[b], s);
}

__global__ void k_losswrite(const float* __restrict__ loss_sums, float* __restrict__ out_loss) {
  int i = threadIdx.x;
  if (i < 8) {
    float v = loss_sums[i] * (1.f/1048576.f);
    out_loss[i] = v;
    out_loss[8 + i] = v;
  }
}

// ---------------- output gather ----------------
__global__ void k_outgather(const float* __restrict__ W2T,
                            const unsigned long long* __restrict__ keys,
                            const float* __restrict__ out_b, float* __restrict__ out)
{
  __shared__ float tile[64][65];
  __shared__ int sj[64];
  int b = blockIdx.y, t0 = blockIdx.x * 64;
  int tid = threadIdx.x;
  if (tid < 64) sj[tid] = (int)(unsigned)(keys[(size_t)b*TT + t0 + tid] & 0xFFFFFFFFull);
  __syncthreads();
  float* ob = out + (size_t)b*DIN*TT;
  int dd = tid & 63, tq = tid >> 6;
  for (int d0 = 0; d0 < DIN; d0 += 64) {
    #pragma unroll
    for (int i = 0; i < 16; i++) {
      int t = tq*16 + i;
      tile[t][dd] = W2T[(size_t)sj[t]*DIN + d0 + dd];
    }
    __syncthreads();
    #pragma unroll
    for (int i = 0; i < 16; i++) {
      int d = tq*16 + i;
      ob[(size_t)(d0+d)*TT + t0 + dd] = tile[dd][d] + out_b[d0+d];
    }
    __syncthreads();
  }
}

// ---------------- launch ----------------
extern "C" void kernel_launch(void* const* d_in, const int* in_sizes, int n_in,
                              void* d_out, int out_size, void* d_ws, size_t ws_size,
                              hipStream_t stream) {
  const float* z        = (const float*)d_in[0];
  const float* in_v     = (const float*)d_in[1];
  const float* in_g     = (const float*)d_in[2];
  const float* in_b     = (const float*)d_in[3];
  const float* out_v    = (const float*)d_in[4];
  const float* out_g    = (const float*)d_in[5];
  const float* out_b    = (const float*)d_in[6];
  const float* codebook = (const float*)d_in[7];

  char* w = (char*)d_ws;
  float* w_in   = (float*)(w + OFF_WIN);
  float* w_outT = (float*)(w + OFF_WOUTT);
  ushort_t* cb_hi = (ushort_t*)(w + OFF_CBN);
  ushort_t* cb_lo = cb_hi + (size_t)CS*DC;
  float* nrm2   = (float*)(w + OFF_NRM2);
  float* z_e    = (float*)(w + OFF_ZE);
  float* inv    = (float*)(w + OFF_INV);
  float* enc2   = (float*)(w + OFF_ENC2);
  unsigned long long* keys = (unsigned long long*)(w + OFF_KEYS);
  float* loss_sums = (float*)(w + OFF_LOSS);
  ushort_t* w_hi = (ushort_t*)(w + OFF_WSPL);
  ushort_t* w_lo = w_hi + (size_t)DC*DIN;
  // region at OFF_W2T: zT hi/lo during z_e GEMM; then enc hi/lo; then
  // W2T (33.6MB) + raw-cb split (8.4MB) + wout split (1MB).
  ushort_t* zt_hi = (ushort_t*)(w + OFF_W2T);
  ushort_t* zt_lo = zt_hi + (size_t)BB*TT*DIN;
  ushort_t* enc_hi = (ushort_t*)(w + OFF_W2T);
  ushort_t* enc_lo = enc_hi + (size_t)BB*TT*DC;
  float* W2T    = (float*)(w + OFF_W2T);
  ushort_t* cbr_hi  = (ushort_t*)(w + OFF_W2T + 33554432);
  ushort_t* cbr_lo  = cbr_hi + (size_t)CS*DC;
  ushort_t* wout_hi = (ushort_t*)(w + OFF_W2T + 33554432 + 8388608);
  ushort_t* wout_lo = wout_hi + (size_t)DIN*DC;

  float* out      = (float*)d_out;
  float* out_loss = out + (size_t)BB*DIN*TT;
  float* out_idx  = out_loss + 16;

  hipMemsetAsync(keys, 0xFF, 32768ull*8, stream);
  hipMemsetAsync(loss_sums, 0, 32, stream);

  const bool mfma_path = (ws_size >= REQ_WS_ZE);

  k_prep_win <<<256, 256, 0, stream>>>(in_v, in_g, w_in, w_hi, w_lo);
  k_prep_cb  <<<8192, 256, 0, stream>>>(codebook, cb_hi, cb_lo, nrm2);

  if (mfma_path) {
    k_split_z<<<dim3(64, 16, 8), 256, 0, stream>>>(z, zt_hi, zt_lo);
    k_ze_mfma<<<dim3(32, 2, 8), 256, 0, stream>>>(zt_hi, zt_lo, w_hi, w_lo, in_b, z_e);
  } else {
    k_prep_wout<<<1024, 256, 0, stream>>>(out_v, out_g, w_outT);
    k_gemm<true><<<dim3(32, 2, 8), 256, 0, stream>>>(
        w_in, z, in_b, z_e, 1024, 1024, 4096, 4096,
        (size_t)DIN*TT, (size_t)DC*TT);
  }

  k_colnorm<<<256, 128, 0, stream>>>(z_e, inv, enc2);
  k_split_enc<<<dim3(64, 4, 8), 256, 0, stream>>>(z_e, inv, enc_hi, enc_lo);

  k_dist_mfma<<<dim3(64, 256), 256, 0, stream>>>(
      enc_hi, enc_lo, cb_hi, cb_lo, nrm2, enc2, keys);

  k_lossidx<<<dim3(64, 8), 256, 0, stream>>>(z_e, codebook, keys, loss_sums, out_idx);
  k_losswrite<<<1, 64, 0, stream>>>(loss_sums, out_loss);

  if (mfma_path) {
    // enc region is dead after dist: build raw-cb / wout splits there, then MFMA W2T.
    k_split_cbraw<<<8192, 256, 0, stream>>>(codebook, cbr_hi, cbr_lo);
    k_split_wout <<<1024, 256, 0, stream>>>(out_v, out_g, wout_hi, wout_lo);
    k_w2t_mfma<<<dim3(64, 8), 256, 0, stream>>>(cbr_hi, cbr_lo, wout_hi, wout_lo, W2T);
  } else {
    k_gemm<false><<<dim3(8, 64, 1), 256, 0, stream>>>(
        codebook, w_outT, nullptr, W2T, 256, 256, 1024, 1024,
        (size_t)0, (size_t)0);
  }

  k_outgather<<<dim3(64, 8), 256, 0, stream>>>(W2T, keys, out_b, out);
}

// Round 5
// 877.799 us; speedup vs baseline: 1.1189x; 1.1189x over previous
//
#include <hip/hip_runtime.h>
#include <stdint.h>

#define BB 8
#define TT 4096
#define DIN 1024
#define DC 256
#define CS 8192
#define EPSF 1e-12f

typedef unsigned short ushort_t;
typedef __attribute__((ext_vector_type(8))) short short8;
typedef __attribute__((ext_vector_type(4))) float f32x4;

// ---------------- workspace layout (bytes) ----------------
constexpr size_t OFF_WIN   = 0;                          // w_in fp32: 1MB (fallback gemm)
constexpr size_t OFF_WOUTT = OFF_WIN   + 1048576;        // fallback: w_outT 1MB | mfma: e2raw/nmraw/n2raw
constexpr size_t OFF_CBN   = OFF_WOUTT + 1048576;        // cb_hi/cb_lo bf16: 8.39MB
constexpr size_t OFF_NRM2  = OFF_CBN   + 8388608;        // nrm2: 32KB
constexpr size_t OFF_ZE    = OFF_NRM2  + 32768;          // fallback: z_e fp32 33.55MB | mfma: enc hi/lo 33.55MB
constexpr size_t OFF_INV   = OFF_ZE    + 33554432;       // inv: 128KB
constexpr size_t OFF_ENC2  = OFF_INV   + 131072;         // enc2: 128KB
constexpr size_t OFF_KEYS  = OFF_ENC2  + 131072;         // keys u64: 256KB
constexpr size_t OFF_LOSS  = OFF_KEYS  + 262144;         // loss: 256B
constexpr size_t OFF_WSPL  = OFF_LOSS  + 256;            // w_hi/w_lo bf16: 1MB
constexpr size_t OFF_W2T   = OFF_WSPL  + 1048576;        // zT(134MB) -> W2T(33.6MB)+cbr/wout splits
constexpr size_t REQ_WS_ZE = OFF_W2T + 134217728ull;     // ~180MB: needed for MFMA path

// ---------------- helpers ----------------
__device__ __forceinline__ float block_reduce_sum_256(float v, float* sbuf) {
  #pragma unroll
  for (int o = 32; o > 0; o >>= 1) v += __shfl_down(v, o, 64);
  int lane = threadIdx.x & 63, w = threadIdx.x >> 6;
  if (lane == 0) sbuf[w] = v;
  __syncthreads();
  float r = sbuf[0] + sbuf[1] + sbuf[2] + sbuf[3];
  __syncthreads();
  return r;
}

__device__ __forceinline__ ushort_t bf16_rne(float x) {
  unsigned u = __float_as_uint(x);
  unsigned r = (u + 0x7FFFu + ((u >> 16) & 1u)) >> 16;
  return (ushort_t)r;
}
__device__ __forceinline__ float bf16f(ushort_t h) {
  return __uint_as_float(((unsigned)h) << 16);
}

// LDS chunk swizzle (proven config across all passing kernels)
__device__ __forceinline__ int swz4(int r) {
  return (r + (r >> 2)) & 3;
}

__device__ __forceinline__ void async_copy16(const ushort_t* g, ushort_t* lds) {
  __builtin_amdgcn_global_load_lds(
      (const __attribute__((address_space(1))) void*)g,
      (__attribute__((address_space(3))) void*)lds, 16, 0, 0);
}

// stage one 128x32 bf16 tile (8KB) into LDS; per-wave; offsets precomputed.
__device__ __forceinline__ void stage_tile8(const ushort_t* __restrict__ s0,
                                            ushort_t* __restrict__ dstbuf,
                                            const int (&go)[8]) {
  #pragma unroll
  for (int i = 0; i < 8; i++) async_copy16(s0 + go[i], dstbuf + i*512);
}

// stage one 256x32 bf16 component tile (16KB) into LDS; 512 threads, 2 loads each.
__device__ __forceinline__ void stage2(const ushort_t* __restrict__ srcbase,
                                       ushort_t* __restrict__ comp,
                                       const int (&go)[2], int wu) {
  async_copy16(srcbase + go[0], comp + wu);
  async_copy16(srcbase + go[1], comp + wu + 4096);
}

#define LD8(base, off) (*(const short8*)((const char*)(base) + (off)))

// one C-quadrant of split-bf16 MFMA: rows MH*4..MH*4+3, cols CLO..CLO+1
template<int MH, int CLO>
__device__ __forceinline__ void qmfma(f32x4 (&acc)[8][4],
    const short8 (&fah)[4], const short8 (&fal)[4],
    const short8 (&fbh)[4], const short8 (&fbl)[4]) {
  #pragma unroll
  for (int r = 0; r < 4; r++) {
    #pragma unroll
    for (int c2 = 0; c2 < 2; c2++) {
      f32x4 t = acc[MH*4 + r][CLO + c2];
      t = __builtin_amdgcn_mfma_f32_16x16x32_bf16(fah[r], fbh[CLO + c2], t, 0, 0, 0);
      t = __builtin_amdgcn_mfma_f32_16x16x32_bf16(fal[r], fbh[CLO + c2], t, 0, 0, 0);
      t = __builtin_amdgcn_mfma_f32_16x16x32_bf16(fah[r], fbl[CLO + c2], t, 0, 0, 0);
      acc[MH*4 + r][CLO + c2] = t;
    }
  }
}

// ---------------- weight prep ----------------
__global__ void k_prep_win(const float* __restrict__ v, const float* __restrict__ g,
                           float* __restrict__ w, ushort_t* __restrict__ wh,
                           ushort_t* __restrict__ wl) {
  __shared__ float sb[4];
  int r = blockIdx.x, t = threadIdx.x;
  float xv[4]; float s = 0.f;
  #pragma unroll
  for (int i = 0; i < 4; i++) { xv[i] = v[r*DIN + t + i*256]; s += xv[i]*xv[i]; }
  s = block_reduce_sum_256(s, sb);
  float sc = g[r] / fmaxf(sqrtf(s), EPSF);
  #pragma unroll
  for (int i = 0; i < 4; i++) {
    float val = xv[i] * sc;
    int idx = r*DIN + t + i*256;
    w[idx] = val;
    ushort_t h = bf16_rne(val);
    wh[idx] = h;
    wl[idx] = bf16_rne(val - bf16f(h));
  }
}

__global__ void k_prep_wout(const float* __restrict__ v, const float* __restrict__ g,
                            float* __restrict__ wT) {
  __shared__ float sb[4];
  int r = blockIdx.x, t = threadIdx.x;
  float x = v[r*DC + t];
  float s = block_reduce_sum_256(x*x, sb);
  float sc = g[r] / fmaxf(sqrtf(s), EPSF);
  wT[t*DIN + r] = x * sc;
}

// normalized cb split + normalized nrm2 + raw norm (nmraw) + raw sum-sq (n2raw)
__global__ void k_prep_cb(const float* __restrict__ cb, ushort_t* __restrict__ cbh,
                          ushort_t* __restrict__ cbl, float* __restrict__ nrm2,
                          float* __restrict__ nmraw, float* __restrict__ n2raw) {
  __shared__ float sb[4];
  int j = blockIdx.x, t = threadIdx.x;
  float x = cb[j*DC + t];
  float s = block_reduce_sum_256(x*x, sb);
  float nm = fmaxf(sqrtf(s), EPSF);
  float cn = x / nm;
  ushort_t h = bf16_rne(cn);
  cbh[j*DC + t] = h;
  cbl[j*DC + t] = bf16_rne(cn - bf16f(h));
  float q = block_reduce_sum_256(cn*cn, sb);
  if (t == 0) { nrm2[j] = q; nmraw[j] = nm; n2raw[j] = s; }
}

// raw codebook bf16 split (for W2T MFMA GEMM)
__global__ void k_split_cbraw(const float* __restrict__ cb, ushort_t* __restrict__ ch,
                              ushort_t* __restrict__ cl) {
  int j = blockIdx.x, t = threadIdx.x;
  float x = cb[j*DC + t];
  ushort_t h = bf16_rne(x);
  ch[j*DC + t] = h;
  cl[j*DC + t] = bf16_rne(x - bf16f(h));
}

// weight-normed out_v, row-major [DIN][DC], bf16 split
__global__ void k_split_wout(const float* __restrict__ v, const float* __restrict__ g,
                             ushort_t* __restrict__ wh, ushort_t* __restrict__ wl) {
  __shared__ float sb[4];
  int r = blockIdx.x, t = threadIdx.x;
  float x = v[r*DC + t];
  float s = block_reduce_sum_256(x*x, sb);
  float sc = g[r] / fmaxf(sqrtf(s), EPSF);
  float val = x * sc;
  ushort_t h = bf16_rne(val);
  wh[r*DC + t] = h;
  wl[r*DC + t] = bf16_rne(val - bf16f(h));
}

// ---------------- fp32 GEMM (fallback path only) ----------------
template<bool BIAS>
__global__ __launch_bounds__(256) void k_gemm(
    const float* __restrict__ A, const float* __restrict__ Bmat,
    const float* __restrict__ bias, float* __restrict__ C,
    int K, int lda, int ldb, int ldc, size_t strideB, size_t strideC)
{
  __shared__ float As[16][132];
  __shared__ float Bs[16][132];
  const int bn = blockIdx.x * 128;
  const int bm = blockIdx.y * 128;
  const float* Bb = Bmat + (size_t)blockIdx.z * strideB;
  float* Cb = C + (size_t)blockIdx.z * strideC;
  const int tid = threadIdx.x;
  const int tx = tid & 15, ty = tid >> 4;
  const int am = tid & 127, akq = (tid >> 7) * 8;
  const int bk = tid >> 5, bj = (tid & 31) * 4;

  float acc[8][8];
  #pragma unroll
  for (int i = 0; i < 8; i++)
    #pragma unroll
    for (int j = 0; j < 8; j++) acc[i][j] = 0.f;

  for (int k0 = 0; k0 < K; k0 += 16) {
    float4 a0 = *(const float4*)&A[(size_t)(bm+am)*lda + k0 + akq];
    float4 a1 = *(const float4*)&A[(size_t)(bm+am)*lda + k0 + akq + 4];
    float4 b0 = *(const float4*)&Bb[(size_t)(k0+bk)*ldb + bn + bj];
    float4 b1 = *(const float4*)&Bb[(size_t)(k0+bk+8)*ldb + bn + bj];
    As[akq+0][am] = a0.x; As[akq+1][am] = a0.y; As[akq+2][am] = a0.z; As[akq+3][am] = a0.w;
    As[akq+4][am] = a1.x; As[akq+5][am] = a1.y; As[akq+6][am] = a1.z; As[akq+7][am] = a1.w;
    *(float4*)&Bs[bk][bj] = b0;
    *(float4*)&Bs[bk+8][bj] = b1;
    __syncthreads();
    #pragma unroll
    for (int k = 0; k < 16; k++) {
      float av[8], bv[8];
      float4 x0 = *(const float4*)&As[k][tx*4];
      float4 x1 = *(const float4*)&As[k][tx*4+64];
      float4 y0 = *(const float4*)&Bs[k][ty*4];
      float4 y1 = *(const float4*)&Bs[k][ty*4+64];
      av[0]=x0.x; av[1]=x0.y; av[2]=x0.z; av[3]=x0.w;
      av[4]=x1.x; av[5]=x1.y; av[6]=x1.z; av[7]=x1.w;
      bv[0]=y0.x; bv[1]=y0.y; bv[2]=y0.z; bv[3]=y0.w;
      bv[4]=y1.x; bv[5]=y1.y; bv[6]=y1.z; bv[7]=y1.w;
      #pragma unroll
      for (int i = 0; i < 8; i++)
        #pragma unroll
        for (int j = 0; j < 8; j++)
          acc[i][j] += av[i] * bv[j];
    }
    __syncthreads();
  }

  #pragma unroll
  for (int i = 0; i < 8; i++) {
    int mm = bm + ((i < 4) ? tx*4 + i : 64 + tx*4 + (i-4));
    float bia = BIAS ? bias[mm] : 0.f;
    float4 v0 = make_float4(acc[i][0]+bia, acc[i][1]+bia, acc[i][2]+bia, acc[i][3]+bia);
    float4 v1 = make_float4(acc[i][4]+bia, acc[i][5]+bia, acc[i][6]+bia, acc[i][7]+bia);
    *(float4*)&Cb[(size_t)mm*ldc + bn + ty*4]      = v0;
    *(float4*)&Cb[(size_t)mm*ldc + bn + 64 + ty*4] = v1;
  }
}

// ---------------- split z: [b][d][t] -> zT hi/lo [b][t][d] ----------------
__global__ void k_split_z(const float* __restrict__ z, ushort_t* __restrict__ zhi,
                          ushort_t* __restrict__ zlo) {
  __shared__ float tile[64][65];
  int b = blockIdx.z, t0 = blockIdx.x * 64, d0 = blockIdx.y * 64;
  int tx = threadIdx.x & 63, ty = threadIdx.x >> 6;
  const float* zb = z + (size_t)b*DIN*TT;
  #pragma unroll
  for (int i = 0; i < 16; i++) {
    int d = i*4 + ty;
    tile[d][tx] = zb[(size_t)(d0+d)*TT + t0 + tx];
  }
  __syncthreads();
  #pragma unroll
  for (int i = 0; i < 16; i++) {
    int t = i*4 + ty;
    float val = tile[tx][t];                 // z[d0+tx][t0+t]
    ushort_t h = bf16_rne(val);
    size_t o = ((size_t)(b*TT + t0 + t))*DIN + d0 + tx;
    zhi[o] = h;
    zlo[o] = bf16_rne(val - bf16f(h));
  }
}

// ---------------- fused z_e GEMM + rownorm + enc split (z_e never stored) ----
// One block owns a 128(t) x 256(c=full DC) stripe: computes z_e in AGPRs,
// reduces e2 = sum_c ze^2 per t IN-BLOCK, and writes normalized bf16-split
// enc [t][c] directly via an LDS transpose bounce. K=DIN=1024, 32 K-steps.
// 8 waves (2x4), per-wave 64x64, acc[4][4]. MFMA order (hh/lh/hl, ascending k)
// identical to the prior passing z_e kernel -> bitwise-identical z_e values.
// grid: (TT/128, B), 512 threads, LDS 96KB staging (reused for the bounce).
__global__ __launch_bounds__(512) void k_ze_enc(
    const ushort_t* __restrict__ zth, const ushort_t* __restrict__ ztl,
    const ushort_t* __restrict__ wh, const ushort_t* __restrict__ wl,
    const float* __restrict__ in_b,
    ushort_t* __restrict__ ehi, ushort_t* __restrict__ elo,
    float* __restrict__ inv, float* __restrict__ enc2, float* __restrict__ e2raw)
{
  __shared__ ushort_t smem[49152];     // 96KB: Ah[2][4096] Al[2][4096] Bh[2][8192] Bl[2][8192]
  __shared__ float e2s[128][4];
  __shared__ float sIv[128];

  ushort_t* sAh = smem;
  ushort_t* sAl = smem + 8192;
  ushort_t* sBh = smem + 16384;
  ushort_t* sBl = smem + 32768;

  const int t0 = blockIdx.x * 128;
  const int b  = blockIdx.y;
  const int tid = threadIdx.x;
  const int lane = tid & 63;
  const int wave = tid >> 6;
  const int wr = wave >> 2, wc = wave & 3;      // 2x4 wave grid
  const int ml = lane & 15, quad = lane >> 4;
  const size_t r0 = (size_t)b*TT + t0;

  const ushort_t* gAh = zth + r0*DIN;
  const ushort_t* gAl = ztl + r0*DIN;

  // A staging: 512 chunks of 16B (128 rows x 32k), 1 per thread
  int goA;
  { int r = tid >> 2, c = tid & 3; int g = c ^ swz4(r); goA = r*DIN + (g << 3); }
  // B staging: 1024 chunks (256 rows x 32k), 2 per thread
  int goB[2];
  #pragma unroll
  for (int l = 0; l < 2; l++) {
    int chunk = l*512 + tid;
    int r = chunk >> 2, c = chunk & 3;
    int g = c ^ swz4(r);
    goB[l] = r*DIN + (g << 3);
  }
  const int wu = wave * 512;

  int offA[4], offB[4];
  #pragma unroll
  for (int i = 0; i < 4; i++) {
    int r = wr*64 + i*16 + ml;
    int p = quad ^ swz4(r);
    offA[i] = r*64 + p*16;
  }
  #pragma unroll
  for (int i = 0; i < 4; i++) {
    int r = wc*64 + i*16 + ml;
    int p = quad ^ swz4(r);
    offB[i] = r*64 + p*16;
  }

  f32x4 acc[4][4];
  #pragma unroll
  for (int i = 0; i < 4; i++)
    #pragma unroll
    for (int j = 0; j < 4; j++) acc[i][j] = (f32x4)0.f;

  // prologue stage K-step 0 into buf 0
  async_copy16(gAh + goA, sAh + wu);
  async_copy16(gAl + goA, sAl + wu);
  stage2(wh, sBh, goB, wu);
  stage2(wl, sBl, goB, wu);

  for (int it = 0; it < 32; ++it) {
    __syncthreads();                           // drains stage(it)
    if (it < 31) {
      const int nb = (it+1) & 1;
      async_copy16(gAh + goA + (it+1)*32, sAh + nb*4096 + wu);
      async_copy16(gAl + goA + (it+1)*32, sAl + nb*4096 + wu);
      stage2(wh + (it+1)*32, sBh + nb*8192, goB, wu);
      stage2(wl + (it+1)*32, sBl + nb*8192, goB, wu);
    }
    const char* pAh = (const char*)(sAh + (it & 1)*4096);
    const char* pAl = (const char*)(sAl + (it & 1)*4096);
    const char* pBh = (const char*)(sBh + (it & 1)*8192);
    const char* pBl = (const char*)(sBl + (it & 1)*8192);

    short8 fbh[4], fbl[4];
    #pragma unroll
    for (int ci = 0; ci < 4; ci++) {
      fbh[ci] = LD8(pBh, offB[ci]);
      fbl[ci] = LD8(pBl, offB[ci]);
    }
    #pragma unroll
    for (int ri = 0; ri < 4; ri++) {
      short8 ah = LD8(pAh, offA[ri]);
      short8 al = LD8(pAl, offA[ri]);
      #pragma unroll
      for (int ci = 0; ci < 4; ci++) {
        acc[ri][ci] = __builtin_amdgcn_mfma_f32_16x16x32_bf16(ah, fbh[ci], acc[ri][ci], 0, 0, 0);
        acc[ri][ci] = __builtin_amdgcn_mfma_f32_16x16x32_bf16(al, fbh[ci], acc[ri][ci], 0, 0, 0);
        acc[ri][ci] = __builtin_amdgcn_mfma_f32_16x16x32_bf16(ah, fbl[ci], acc[ri][ci], 0, 0, 0);
      }
    }
  }

  // ---- add bias; per-t e2 partials (deterministic: shfl tree + fixed slots) ----
  float bia[4];
  #pragma unroll
  for (int ci = 0; ci < 4; ci++) bia[ci] = in_b[wc*64 + ci*16 + ml];

  #pragma unroll
  for (int ri = 0; ri < 4; ri++) {
    #pragma unroll
    for (int reg = 0; reg < 4; reg++) {
      float p = 0.f;
      #pragma unroll
      for (int ci = 0; ci < 4; ci++) {
        float v = acc[ri][ci][reg] + bia[ci];
        acc[ri][ci][reg] = v;
        p += v*v;
      }
      #pragma unroll
      for (int off = 1; off < 16; off <<= 1) p += __shfl_xor(p, off);
      if (ml == 0) e2s[wr*64 + ri*16 + quad*4 + reg][wc] = p;
    }
  }
  __syncthreads();
  if (tid < 128) {
    float s = ((e2s[tid][0] + e2s[tid][1]) + e2s[tid][2]) + e2s[tid][3];
    float iv = 1.f / fmaxf(sqrtf(s), EPSF);
    sIv[tid] = iv;
    inv[r0 + tid]   = iv;
    enc2[r0 + tid]  = (s * iv) * iv;
    e2raw[r0 + tid] = s;
  }
  __syncthreads();

  // ---- enc write via LDS transpose bounce (2 passes: hi then lo) ----
  ushort_t* tb = smem;                          // reuse staging as [128][256]
  #pragma unroll
  for (int ri = 0; ri < 4; ri++) {
    #pragma unroll
    for (int reg = 0; reg < 4; reg++) {
      int t_loc = wr*64 + ri*16 + quad*4 + reg;
      float ivt = sIv[t_loc];
      #pragma unroll
      for (int ci = 0; ci < 4; ci++) {
        int c_loc = wc*64 + ci*16 + ml;
        tb[t_loc*256 + c_loc] = bf16_rne(acc[ri][ci][reg] * ivt);
      }
    }
  }
  __syncthreads();
  #pragma unroll
  for (int p = 0; p < 8; p++) {
    int ch = p*512 + tid;
    *(short8*)(ehi + r0*DC + (size_t)ch*8) = *(const short8*)(tb + ch*8);
  }
  __syncthreads();
  #pragma unroll
  for (int ri = 0; ri < 4; ri++) {
    #pragma unroll
    for (int reg = 0; reg < 4; reg++) {
      int t_loc = wr*64 + ri*16 + quad*4 + reg;
      float ivt = sIv[t_loc];
      #pragma unroll
      for (int ci = 0; ci < 4; ci++) {
        int c_loc = wc*64 + ci*16 + ml;
        float v = acc[ri][ci][reg] * ivt;
        ushort_t h = bf16_rne(v);
        tb[t_loc*256 + c_loc] = bf16_rne(v - bf16f(h));
      }
    }
  }
  __syncthreads();
  #pragma unroll
  for (int p = 0; p < 8; p++) {
    int ch = p*512 + tid;
    *(short8*)(elo + r0*DC + (size_t)ch*8) = *(const short8*)(tb + ch*8);
  }
}

// ---------------- W2T via split-bf16 MFMA ----------------
__global__ __launch_bounds__(256) void k_w2t_mfma(
    const ushort_t* __restrict__ ah_g, const ushort_t* __restrict__ al_g,
    const ushort_t* __restrict__ bh_g, const ushort_t* __restrict__ bl_g,
    float* __restrict__ C)
{
  __shared__ ushort_t As_hi[2][4096];
  __shared__ ushort_t As_lo[2][4096];
  __shared__ ushort_t Bs_hi[2][4096];
  __shared__ ushort_t Bs_lo[2][4096];

  const int m0 = blockIdx.x * 128;
  const int n0 = blockIdx.y * 128;
  const int tid = threadIdx.x;
  const int lane = tid & 63;
  const int wave = tid >> 6;
  const int wr = wave >> 1, wc = wave & 1;
  const int m = lane & 15, quad = lane >> 4;

  const ushort_t* src; ushort_t* dst;
  {
    size_t aoff = (size_t)m0 * DC;
    size_t boff = (size_t)n0 * DC;
    if      (wave == 0) { src = ah_g + aoff; dst = &As_hi[0][0]; }
    else if (wave == 1) { src = al_g + aoff; dst = &As_lo[0][0]; }
    else if (wave == 2) { src = bh_g + boff; dst = &Bs_hi[0][0]; }
    else                { src = bl_g + boff; dst = &Bs_lo[0][0]; }
  }
  const int rr = lane >> 2, cc = lane & 3;

  int goT[8];
  #pragma unroll
  for (int i = 0; i < 8; i++) {
    int r = i*16 + rr;
    int g = cc ^ swz4(r);
    goT[i] = r*DC + (g << 3);
  }

  int offA[4], offB[4];
  #pragma unroll
  for (int ri = 0; ri < 4; ri++) {
    int r = wr*64 + ri*16 + m;
    int p = quad ^ swz4(r);
    offA[ri] = r*64 + p*16;
  }
  #pragma unroll
  for (int ci = 0; ci < 4; ci++) {
    int r = wc*64 + ci*16 + m;
    int p = quad ^ swz4(r);
    offB[ci] = r*64 + p*16;
  }

  f32x4 acc[4][4];
  #pragma unroll
  for (int i = 0; i < 4; i++)
    #pragma unroll
    for (int j = 0; j < 4; j++) acc[i][j] = (f32x4)0.f;

  stage_tile8(src, dst, goT);

  for (int it = 0; it < 8; ++it) {
    __syncthreads();
    if (it < 7) stage_tile8(src + (it+1)*32, dst + ((it+1)&1)*4096, goT);
    const int bo = (it & 1) << 13;

    short8 bh[4], bl[4];
    #pragma unroll
    for (int ci = 0; ci < 4; ci++) {
      bh[ci] = *(const short8*)((const char*)Bs_hi + bo + offB[ci]);
      bl[ci] = *(const short8*)((const char*)Bs_lo + bo + offB[ci]);
    }
    #pragma unroll
    for (int ri = 0; ri < 4; ri++) {
      short8 ah = *(const short8*)((const char*)As_hi + bo + offA[ri]);
      short8 al = *(const short8*)((const char*)As_lo + bo + offA[ri]);
      #pragma unroll
      for (int ci = 0; ci < 4; ci++) {
        acc[ri][ci] = __builtin_amdgcn_mfma_f32_16x16x32_bf16(ah, bh[ci], acc[ri][ci], 0, 0, 0);
        acc[ri][ci] = __builtin_amdgcn_mfma_f32_16x16x32_bf16(al, bh[ci], acc[ri][ci], 0, 0, 0);
        acc[ri][ci] = __builtin_amdgcn_mfma_f32_16x16x32_bf16(ah, bl[ci], acc[ri][ci], 0, 0, 0);
      }
    }
  }

  #pragma unroll
  for (int ri = 0; ri < 4; ri++) {
    int m_loc = wr*64 + ri*16 + quad*4;
    #pragma unroll
    for (int ci = 0; ci < 4; ci++) {
      int n_loc = wc*64 + ci*16 + m;
      #pragma unroll
      for (int reg = 0; reg < 4; reg++) {
        C[(size_t)(m0 + m_loc + reg)*DIN + n0 + n_loc] = acc[ri][ci][reg];
      }
    }
  }
}

// ---------------- fallback-only: column norms + enc split + loss ----------------
__global__ void k_colnorm(const float* __restrict__ ze, float* __restrict__ inv,
                          float* __restrict__ enc2) {
  int r = blockIdx.x * 128 + threadIdx.x;
  int b = r >> 12, t = r & 4095;
  const float* p = ze + (size_t)b*DC*TT + t;
  float s = 0.f;
  for (int c = 0; c < DC; c++) { float x = p[(size_t)c*TT]; s += x*x; }
  float iv = 1.f / fmaxf(sqrtf(s), EPSF);
  inv[r] = iv;
  enc2[r] = (s * iv) * iv;
}

__global__ void k_split_enc(const float* __restrict__ ze, const float* __restrict__ inv,
                            ushort_t* __restrict__ ehi, ushort_t* __restrict__ elo) {
  __shared__ float tile[64][65];
  int b = blockIdx.z, t0 = blockIdx.x * 64, c0 = blockIdx.y * 64;
  int tx = threadIdx.x & 63, ty = threadIdx.x >> 6;
  const float* zb = ze + (size_t)b*DC*TT;
  #pragma unroll
  for (int i = 0; i < 16; i++) {
    int c = i*4 + ty;
    tile[c][tx] = zb[(size_t)(c0+c)*TT + t0 + tx];
  }
  __syncthreads();
  #pragma unroll
  for (int i = 0; i < 16; i++) {
    int t = i*4 + ty;
    float iv = inv[b*TT + t0 + t];
    float val = tile[tx][t] * iv;
    ushort_t h = bf16_rne(val);
    size_t o = ((size_t)(b*TT + t0 + t))*DC + c0 + tx;
    ehi[o] = h;
    elo[o] = bf16_rne(val - bf16f(h));
  }
}

__global__ void k_lossidx(const float* __restrict__ ze, const float* __restrict__ cb,
                          const unsigned long long* __restrict__ keys,
                          float* __restrict__ loss_sums, float* __restrict__ out_idx)
{
  __shared__ float sb[4];
  __shared__ int sj[64];
  int b = blockIdx.y, t0 = blockIdx.x * 64;
  int tid = threadIdx.x;
  if (tid < 64) {
    unsigned long long k = keys[(size_t)b*TT + t0 + tid];
    int j = (int)(unsigned)(k & 0xFFFFFFFFull);
    sj[tid] = j;
    out_idx[(size_t)b*TT + t0 + tid] = (float)j;
  }
  __syncthreads();
  int tt = tid & 63, tc = tid >> 6;
  const float* zb = ze + (size_t)b*DC*TT + t0;
  int j = sj[tt];
  float s = 0.f;
  for (int ci = 0; ci < 64; ci++) {
    int c = tc + ci*4;
    float zev = zb[(size_t)c*TT + tt];
    float zqv = cb[(size_t)j*DC + c];
    float d = zev - zqv;
    s += d*d;
  }
  s = block_reduce_sum_256(s, sb);
  if (tid == 0) atomicAdd(&loss_sums[b], s);
}

// ---------------- fused distance + argmin (R3-proven: 492us) ----------------
__global__ __launch_bounds__(512, 2) void k_dist_mfma(
    const ushort_t* __restrict__ ehi, const ushort_t* __restrict__ elo,
    const ushort_t* __restrict__ cbh, const ushort_t* __restrict__ cbl,
    const float* __restrict__ nrm2, const float* __restrict__ enc2,
    unsigned long long* __restrict__ keys)
{
  __shared__ ushort_t sAh[2][8192];
  __shared__ ushort_t sAl[2][8192];
  __shared__ ushort_t sBh[2][8192];
  __shared__ ushort_t sBl[2][8192];
  __shared__ float sE2[256], sN2[256];
  __shared__ unsigned long long rkey[256];

  const int j0 = blockIdx.x * 256;
  const size_t r0 = (size_t)blockIdx.y * 256;
  const int tid = threadIdx.x;
  const int lane = tid & 63;
  const int wave = tid >> 6;
  const int wr = wave >> 2, wc = wave & 3;
  const int ml = lane & 15, quad = lane >> 4;

  if (tid < 256) {
    sE2[tid] = enc2[r0 + tid];
    sN2[tid] = nrm2[j0 + tid];
    rkey[tid] = 0xFFFFFFFFFFFFFFFFull;
  }

  const ushort_t* gAh = ehi + r0 * DC;
  const ushort_t* gAl = elo + r0 * DC;
  const ushort_t* gBh = cbh + (size_t)j0 * DC;
  const ushort_t* gBl = cbl + (size_t)j0 * DC;

  int goS[2];
  #pragma unroll
  for (int l = 0; l < 2; l++) {
    int chunk = l*512 + tid;
    int r = chunk >> 2, c = chunk & 3;
    int g = c ^ swz4(r);
    goS[l] = r*DC + (g << 3);
  }
  const int wu = wave * 512;

  int offA[8], offB[4];
  #pragma unroll
  for (int i = 0; i < 8; i++) {
    int r = wr*128 + i*16 + ml;
    int p = quad ^ swz4(r);
    offA[i] = r*64 + p*16;
  }
  #pragma unroll
  for (int i = 0; i < 4; i++) {
    int r = wc*64 + i*16 + ml;
    int p = quad ^ swz4(r);
    offB[i] = r*64 + p*16;
  }

  f32x4 acc[8][4];
  #pragma unroll
  for (int i = 0; i < 8; i++)
    #pragma unroll
    for (int j = 0; j < 4; j++) acc[i][j] = (f32x4)0.f;

  stage2(gBh,      &sBh[0][0], goS, wu);
  stage2(gBl,      &sBl[0][0], goS, wu);
  stage2(gAh,      &sAh[0][0], goS, wu);
  stage2(gAl,      &sAl[0][0], goS, wu);
  stage2(gBh + 32, &sBh[1][0], goS, wu);
  stage2(gBl + 32, &sBl[1][0], goS, wu);
  asm volatile("s_waitcnt vmcnt(4)" ::: "memory");
  asm volatile("s_waitcnt lgkmcnt(0)" ::: "memory");
  __builtin_amdgcn_s_barrier();
  __builtin_amdgcn_sched_barrier(0);

  short8 fa_h[4], fa_l[4], fb_h[4], fb_l[4];

  #pragma unroll 2
  for (int k = 0; k < 8; k++) {
    const int cb = k & 1, nb = cb ^ 1;
    const char* pAh = (const char*)&sAh[cb][0];
    const char* pAl = (const char*)&sAl[cb][0];
    const char* pBh = (const char*)&sBh[cb][0];
    const char* pBl = (const char*)&sBl[cb][0];
    __builtin_amdgcn_sched_barrier(0);

    #pragma unroll
    for (int i = 0; i < 4; i++) { fa_h[i] = LD8(pAh, offA[i]); fa_l[i] = LD8(pAl, offA[i]); }
    #pragma unroll
    for (int i = 0; i < 2; i++) { fb_h[i] = LD8(pBh, offB[i]); fb_l[i] = LD8(pBl, offB[i]); }
    if (k < 7) stage2(gAh + (size_t)(k+1)*32, &sAh[nb][0], goS, wu);
    __builtin_amdgcn_s_barrier();
    __builtin_amdgcn_s_setprio(1);
    qmfma<0, 0>(acc, fa_h, fa_l, fb_h, fb_l);
    __builtin_amdgcn_s_setprio(0);
    __builtin_amdgcn_s_barrier();

    #pragma unroll
    for (int i = 2; i < 4; i++) { fb_h[i] = LD8(pBh, offB[i]); fb_l[i] = LD8(pBl, offB[i]); }
    if (k < 7) stage2(gAl + (size_t)(k+1)*32, &sAl[nb][0], goS, wu);
    __builtin_amdgcn_s_barrier();
    __builtin_amdgcn_s_setprio(1);
    qmfma<0, 2>(acc, fa_h, fa_l, fb_h, fb_l);
    __builtin_amdgcn_s_setprio(0);
    __builtin_amdgcn_s_barrier();

    #pragma unroll
    for (int i = 0; i < 4; i++) { fa_h[i] = LD8(pAh, offA[4+i]); fa_l[i] = LD8(pAl, offA[4+i]); }
    if (k < 6) {
      stage2(gBh + (size_t)(k+2)*32, &sBh[cb][0], goS, wu);
      stage2(gBl + (size_t)(k+2)*32, &sBl[cb][0], goS, wu);
    }
    __builtin_amdgcn_s_barrier();
    __builtin_amdgcn_s_setprio(1);
    qmfma<1, 2>(acc, fa_h, fa_l, fb_h, fb_l);
    qmfma<1, 0>(acc, fa_h, fa_l, fb_h, fb_l);
    __builtin_amdgcn_s_setprio(0);
    if (k < 6) { asm volatile("s_waitcnt vmcnt(4)" ::: "memory"); }
    else       { asm volatile("s_waitcnt vmcnt(0)" ::: "memory"); }
    __builtin_amdgcn_s_barrier();
  }

  #pragma unroll
  for (int ri = 0; ri < 8; ri++) {
    #pragma unroll
    for (int reg = 0; reg < 4; reg++) {
      int t_loc = wr*128 + ri*16 + quad*4 + reg;
      float e2 = sE2[t_loc];
      unsigned long long best = 0xFFFFFFFFFFFFFFFFull;
      #pragma unroll
      for (int ci = 0; ci < 4; ci++) {
        int j_loc = wc*64 + ci*16 + ml;
        float d = e2 - 2.0f * acc[ri][ci][reg];
        d = d + sN2[j_loc];
        unsigned long long key =
            ((unsigned long long)__float_as_uint(d) << 32) | (unsigned)(j0 + j_loc);
        best = key < best ? key : best;
      }
      #pragma unroll
      for (int off = 1; off < 16; off <<= 1) {
        unsigned long long o = __shfl_xor(best, off);
        best = o < best ? o : best;
      }
      if (ml == 0) atomicMin(&rkey[t_loc], best);
    }
  }
  __syncthreads();
  if (tid < 256) atomicMin(&keys[r0 + tid], rkey[tid]);
}

// ---------------- loss reconstruction (no z_e needed) ----------------
// sum_c (ze - cb_j)^2 = e2raw - 2*nm_j*dotn/iv_t + n2raw_j,
// dotn = (enc2 + nrm2_j - d)/2 recovered from the dist key.
__global__ void k_lossrec(const unsigned long long* __restrict__ keys,
                          const float* __restrict__ enc2, const float* __restrict__ nrm2,
                          const float* __restrict__ e2raw, const float* __restrict__ inv,
                          const float* __restrict__ nmraw, const float* __restrict__ n2raw,
                          float* __restrict__ loss_sums, float* __restrict__ out_idx)
{
  __shared__ float sb[4];
  int r = blockIdx.x * 256 + threadIdx.x;
  int b = r >> 12;
  unsigned long long k = keys[r];
  int j = (int)(unsigned)(k & 0xFFFFFFFFull);
  float d = __uint_as_float((unsigned)(k >> 32));
  out_idx[r] = (float)j;
  float dotn = 0.5f * (enc2[r] + nrm2[j] - d);
  float dot_raw = nmraw[j] * dotn / inv[r];
  float le = e2raw[r] - 2.f*dot_raw + n2raw[j];
  float s = block_reduce_sum_256(le, sb);
  if (threadIdx.x == 0) atomicAdd(&loss_sums[b], s);
}

__global__ void k_losswrite(const float* __restrict__ loss_sums, float* __restrict__ out_loss) {
  int i = threadIdx.x;
  if (i < 8) {
    float v = loss_sums[i] * (1.f/1048576.f);
    out_loss[i] = v;
    out_loss[8 + i] = v;
  }
}

// ---------------- output gather ----------------
__global__ void k_outgather(const float* __restrict__ W2T,
                            const unsigned long long* __restrict__ keys,
                            const float* __restrict__ out_b, float* __restrict__ out)
{
  __shared__ float tile[64][65];
  __shared__ int sj[64];
  int b = blockIdx.y, t0 = blockIdx.x * 64;
  int tid = threadIdx.x;
  if (tid < 64) sj[tid] = (int)(unsigned)(keys[(size_t)b*TT + t0 + tid] & 0xFFFFFFFFull);
  __syncthreads();
  float* ob = out + (size_t)b*DIN*TT;
  int dd = tid & 63, tq = tid >> 6;
  for (int d0 = 0; d0 < DIN; d0 += 64) {
    #pragma unroll
    for (int i = 0; i < 16; i++) {
      int t = tq*16 + i;
      tile[t][dd] = W2T[(size_t)sj[t]*DIN + d0 + dd];
    }
    __syncthreads();
    #pragma unroll
    for (int i = 0; i < 16; i++) {
      int d = tq*16 + i;
      ob[(size_t)(d0+d)*TT + t0 + dd] = tile[dd][d] + out_b[d0+d];
    }
    __syncthreads();
  }
}

// ---------------- launch ----------------
extern "C" void kernel_launch(void* const* d_in, const int* in_sizes, int n_in,
                              void* d_out, int out_size, void* d_ws, size_t ws_size,
                              hipStream_t stream) {
  const float* z        = (const float*)d_in[0];
  const float* in_v     = (const float*)d_in[1];
  const float* in_g     = (const float*)d_in[2];
  const float* in_b     = (const float*)d_in[3];
  const float* out_v    = (const float*)d_in[4];
  const float* out_g    = (const float*)d_in[5];
  const float* out_b    = (const float*)d_in[6];
  const float* codebook = (const float*)d_in[7];

  char* w = (char*)d_ws;
  float* w_in   = (float*)(w + OFF_WIN);
  float* w_outT = (float*)(w + OFF_WOUTT);               // fallback only
  float* e2raw  = (float*)(w + OFF_WOUTT);               // mfma only (aliases w_outT)
  float* nmraw  = (float*)(w + OFF_WOUTT + 131072);
  float* n2raw  = (float*)(w + OFF_WOUTT + 163840);
  ushort_t* cb_hi = (ushort_t*)(w + OFF_CBN);
  ushort_t* cb_lo = cb_hi + (size_t)CS*DC;
  float* nrm2   = (float*)(w + OFF_NRM2);
  float* z_e    = (float*)(w + OFF_ZE);                  // fallback only
  ushort_t* enc_hi_m = (ushort_t*)(w + OFF_ZE);          // mfma only (aliases z_e)
  ushort_t* enc_lo_m = enc_hi_m + (size_t)BB*TT*DC;
  float* inv    = (float*)(w + OFF_INV);
  float* enc2   = (float*)(w + OFF_ENC2);
  unsigned long long* keys = (unsigned long long*)(w + OFF_KEYS);
  float* loss_sums = (float*)(w + OFF_LOSS);
  ushort_t* w_hi = (ushort_t*)(w + OFF_WSPL);
  ushort_t* w_lo = w_hi + (size_t)DC*DIN;
  // OFF_W2T region: zT hi/lo during ze_enc; then W2T + cbr/wout splits.
  ushort_t* zt_hi = (ushort_t*)(w + OFF_W2T);
  ushort_t* zt_lo = zt_hi + (size_t)BB*TT*DIN;
  ushort_t* enc_hi_fb = (ushort_t*)(w + OFF_W2T);        // fallback enc location
  ushort_t* enc_lo_fb = enc_hi_fb + (size_t)BB*TT*DC;
  float* W2T    = (float*)(w + OFF_W2T);
  ushort_t* cbr_hi  = (ushort_t*)(w + OFF_W2T + 33554432);
  ushort_t* cbr_lo  = cbr_hi + (size_t)CS*DC;
  ushort_t* wout_hi = (ushort_t*)(w + OFF_W2T + 33554432 + 8388608);
  ushort_t* wout_lo = wout_hi + (size_t)DIN*DC;

  float* out      = (float*)d_out;
  float* out_loss = out + (size_t)BB*DIN*TT;
  float* out_idx  = out_loss + 16;

  hipMemsetAsync(keys, 0xFF, 32768ull*8, stream);
  hipMemsetAsync(loss_sums, 0, 32, stream);

  const bool mfma_path = (ws_size >= REQ_WS_ZE);

  k_prep_win <<<256, 256, 0, stream>>>(in_v, in_g, w_in, w_hi, w_lo);
  k_prep_cb  <<<8192, 256, 0, stream>>>(codebook, cb_hi, cb_lo, nrm2, nmraw, n2raw);

  if (mfma_path) {
    k_split_z<<<dim3(64, 16, 8), 256, 0, stream>>>(z, zt_hi, zt_lo);
    k_ze_enc<<<dim3(32, 8), 512, 0, stream>>>(
        zt_hi, zt_lo, w_hi, w_lo, in_b, enc_hi_m, enc_lo_m, inv, enc2, e2raw);

    k_dist_mfma<<<dim3(32, 128), 512, 0, stream>>>(
        enc_hi_m, enc_lo_m, cb_hi, cb_lo, nrm2, enc2, keys);

    k_lossrec<<<128, 256, 0, stream>>>(
        keys, enc2, nrm2, e2raw, inv, nmraw, n2raw, loss_sums, out_idx);
    k_losswrite<<<1, 64, 0, stream>>>(loss_sums, out_loss);

    // zt region dead after ze_enc: build W2T there via MFMA.
    k_split_cbraw<<<8192, 256, 0, stream>>>(codebook, cbr_hi, cbr_lo);
    k_split_wout <<<1024, 256, 0, stream>>>(out_v, out_g, wout_hi, wout_lo);
    k_w2t_mfma<<<dim3(64, 8), 256, 0, stream>>>(cbr_hi, cbr_lo, wout_hi, wout_lo, W2T);
  } else {
    k_prep_wout<<<1024, 256, 0, stream>>>(out_v, out_g, w_outT);
    k_gemm<true><<<dim3(32, 2, 8), 256, 0, stream>>>(
        w_in, z, in_b, z_e, 1024, 1024, 4096, 4096,
        (size_t)DIN*TT, (size_t)DC*TT);
    k_colnorm<<<256, 128, 0, stream>>>(z_e, inv, enc2);
    k_split_enc<<<dim3(64, 4, 8), 256, 0, stream>>>(z_e, inv, enc_hi_fb, enc_lo_fb);

    k_dist_mfma<<<dim3(32, 128), 512, 0, stream>>>(
        enc_hi_fb, enc_lo_fb, cb_hi, cb_lo, nrm2, enc2, keys);

    k_lossidx<<<dim3(64, 8), 256, 0, stream>>>(z_e, codebook, keys, loss_sums, out_idx);
    k_losswrite<<<1, 64, 0, stream>>>(loss_sums, out_loss);

    k_gemm<false><<<dim3(8, 64, 1), 256, 0, stream>>>(
        codebook, w_outT, nullptr, W2T, 256, 256, 1024, 1024,
        (size_t)0, (size_t)0);
  }

  k_outgather<<<dim3(64, 8), 256, 0, stream>>>(W2T, keys, out_b, out);
}

// Round 6
// 830.762 us; speedup vs baseline: 1.1823x; 1.0566x over previous
//
#include <hip/hip_runtime.h>
#include <stdint.h>

#define BB 8
#define TT 4096
#define DIN 1024
#define DC 256
#define CS 8192
#define EPSF 1e-12f

typedef unsigned short ushort_t;
typedef __attribute__((ext_vector_type(8))) short short8;
typedef __attribute__((ext_vector_type(4))) float f32x4;

// ---------------- workspace layout (bytes) ----------------
constexpr size_t OFF_WIN   = 0;                          // w_in fp32: 1MB (fallback gemm)
constexpr size_t OFF_WOUTT = OFF_WIN   + 1048576;        // fallback: w_outT 1MB | mfma: e2raw/nmraw/n2raw
constexpr size_t OFF_CBN   = OFF_WOUTT + 1048576;        // cb_hi/cb_lo bf16: 8.39MB
constexpr size_t OFF_NRM2  = OFF_CBN   + 8388608;        // nrm2: 32KB
constexpr size_t OFF_ZE    = OFF_NRM2  + 32768;          // fallback: z_e fp32 33.55MB | mfma: enc hi/lo 33.55MB
constexpr size_t OFF_INV   = OFF_ZE    + 33554432;       // inv: 128KB
constexpr size_t OFF_ENC2  = OFF_INV   + 131072;         // enc2: 128KB
constexpr size_t OFF_KEYS  = OFF_ENC2  + 131072;         // keys u64: 256KB
constexpr size_t OFF_LOSS  = OFF_KEYS  + 262144;         // loss: 256B
constexpr size_t OFF_WSPL  = OFF_LOSS  + 256;            // w_hi/w_lo bf16: 1MB
constexpr size_t OFF_W2T   = OFF_WSPL  + 1048576;        // W2T(33.6MB) + cbr(8.4MB) + wout(1MB) splits
constexpr size_t REQ_WS_ZE = OFF_W2T + 134217728ull;     // keep same threshold as prior rounds

// ---------------- helpers ----------------
__device__ __forceinline__ float block_reduce_sum_256(float v, float* sbuf) {
  #pragma unroll
  for (int o = 32; o > 0; o >>= 1) v += __shfl_down(v, o, 64);
  int lane = threadIdx.x & 63, w = threadIdx.x >> 6;
  if (lane == 0) sbuf[w] = v;
  __syncthreads();
  float r = sbuf[0] + sbuf[1] + sbuf[2] + sbuf[3];
  __syncthreads();
  return r;
}

__device__ __forceinline__ ushort_t bf16_rne(float x) {
  unsigned u = __float_as_uint(x);
  unsigned r = (u + 0x7FFFu + ((u >> 16) & 1u)) >> 16;
  return (ushort_t)r;
}
__device__ __forceinline__ float bf16f(ushort_t h) {
  return __uint_as_float(((unsigned)h) << 16);
}

// LDS chunk swizzle (proven config across all passing kernels).
// Invariant: LDS quad c of row r holds global 8-elem chunk c ^ swz4(r).
__device__ __forceinline__ int swz4(int r) {
  return (r + (r >> 2)) & 3;
}

__device__ __forceinline__ void async_copy16(const ushort_t* g, ushort_t* lds) {
  __builtin_amdgcn_global_load_lds(
      (const __attribute__((address_space(1))) void*)g,
      (__attribute__((address_space(3))) void*)lds, 16, 0, 0);
}

// stage one 128x32 bf16 tile (8KB) into LDS; per-wave; offsets precomputed.
__device__ __forceinline__ void stage_tile8(const ushort_t* __restrict__ s0,
                                            ushort_t* __restrict__ dstbuf,
                                            const int (&go)[8]) {
  #pragma unroll
  for (int i = 0; i < 8; i++) async_copy16(s0 + go[i], dstbuf + i*512);
}

// stage one 256x32 bf16 component tile (16KB) into LDS; 512 threads, 2 loads each.
__device__ __forceinline__ void stage2(const ushort_t* __restrict__ srcbase,
                                       ushort_t* __restrict__ comp,
                                       const int (&go)[2], int wu) {
  async_copy16(srcbase + go[0], comp + wu);
  async_copy16(srcbase + go[1], comp + wu + 4096);
}

#define LD8(base, off) (*(const short8*)((const char*)(base) + (off)))

// one C-quadrant of split-bf16 MFMA: rows MH*4..MH*4+3, cols CLO..CLO+1
template<int MH, int CLO>
__device__ __forceinline__ void qmfma(f32x4 (&acc)[8][4],
    const short8 (&fah)[4], const short8 (&fal)[4],
    const short8 (&fbh)[4], const short8 (&fbl)[4]) {
  #pragma unroll
  for (int r = 0; r < 4; r++) {
    #pragma unroll
    for (int c2 = 0; c2 < 2; c2++) {
      f32x4 t = acc[MH*4 + r][CLO + c2];
      t = __builtin_amdgcn_mfma_f32_16x16x32_bf16(fah[r], fbh[CLO + c2], t, 0, 0, 0);
      t = __builtin_amdgcn_mfma_f32_16x16x32_bf16(fal[r], fbh[CLO + c2], t, 0, 0, 0);
      t = __builtin_amdgcn_mfma_f32_16x16x32_bf16(fah[r], fbl[CLO + c2], t, 0, 0, 0);
      acc[MH*4 + r][CLO + c2] = t;
    }
  }
}

// ---------------- weight prep ----------------
__global__ void k_prep_win(const float* __restrict__ v, const float* __restrict__ g,
                           float* __restrict__ w, ushort_t* __restrict__ wh,
                           ushort_t* __restrict__ wl) {
  __shared__ float sb[4];
  int r = blockIdx.x, t = threadIdx.x;
  float xv[4]; float s = 0.f;
  #pragma unroll
  for (int i = 0; i < 4; i++) { xv[i] = v[r*DIN + t + i*256]; s += xv[i]*xv[i]; }
  s = block_reduce_sum_256(s, sb);
  float sc = g[r] / fmaxf(sqrtf(s), EPSF);
  #pragma unroll
  for (int i = 0; i < 4; i++) {
    float val = xv[i] * sc;
    int idx = r*DIN + t + i*256;
    w[idx] = val;
    ushort_t h = bf16_rne(val);
    wh[idx] = h;
    wl[idx] = bf16_rne(val - bf16f(h));
  }
}

__global__ void k_prep_wout(const float* __restrict__ v, const float* __restrict__ g,
                            float* __restrict__ wT) {
  __shared__ float sb[4];
  int r = blockIdx.x, t = threadIdx.x;
  float x = v[r*DC + t];
  float s = block_reduce_sum_256(x*x, sb);
  float sc = g[r] / fmaxf(sqrtf(s), EPSF);
  wT[t*DIN + r] = x * sc;
}

// normalized cb split + nrm2 + raw norm/sumsq + RAW bf16 split (one codebook read)
__global__ void k_prep_cb(const float* __restrict__ cb, ushort_t* __restrict__ cbh,
                          ushort_t* __restrict__ cbl, float* __restrict__ nrm2,
                          float* __restrict__ nmraw, float* __restrict__ n2raw,
                          ushort_t* __restrict__ crh, ushort_t* __restrict__ crl) {
  __shared__ float sb[4];
  int j = blockIdx.x, t = threadIdx.x;
  float x = cb[j*DC + t];
  ushort_t hr = bf16_rne(x);
  crh[j*DC + t] = hr;
  crl[j*DC + t] = bf16_rne(x - bf16f(hr));
  float s = block_reduce_sum_256(x*x, sb);
  float nm = fmaxf(sqrtf(s), EPSF);
  float cn = x / nm;
  ushort_t h = bf16_rne(cn);
  cbh[j*DC + t] = h;
  cbl[j*DC + t] = bf16_rne(cn - bf16f(h));
  float q = block_reduce_sum_256(cn*cn, sb);
  if (t == 0) { nrm2[j] = q; nmraw[j] = nm; n2raw[j] = s; }
}

// weight-normed out_v, row-major [DIN][DC], bf16 split
__global__ void k_split_wout(const float* __restrict__ v, const float* __restrict__ g,
                             ushort_t* __restrict__ wh, ushort_t* __restrict__ wl) {
  __shared__ float sb[4];
  int r = blockIdx.x, t = threadIdx.x;
  float x = v[r*DC + t];
  float s = block_reduce_sum_256(x*x, sb);
  float sc = g[r] / fmaxf(sqrtf(s), EPSF);
  float val = x * sc;
  ushort_t h = bf16_rne(val);
  wh[r*DC + t] = h;
  wl[r*DC + t] = bf16_rne(val - bf16f(h));
}

// ---------------- fp32 GEMM (fallback path only) ----------------
template<bool BIAS>
__global__ __launch_bounds__(256) void k_gemm(
    const float* __restrict__ A, const float* __restrict__ Bmat,
    const float* __restrict__ bias, float* __restrict__ C,
    int K, int lda, int ldb, int ldc, size_t strideB, size_t strideC)
{
  __shared__ float As[16][132];
  __shared__ float Bs[16][132];
  const int bn = blockIdx.x * 128;
  const int bm = blockIdx.y * 128;
  const float* Bb = Bmat + (size_t)blockIdx.z * strideB;
  float* Cb = C + (size_t)blockIdx.z * strideC;
  const int tid = threadIdx.x;
  const int tx = tid & 15, ty = tid >> 4;
  const int am = tid & 127, akq = (tid >> 7) * 8;
  const int bk = tid >> 5, bj = (tid & 31) * 4;

  float acc[8][8];
  #pragma unroll
  for (int i = 0; i < 8; i++)
    #pragma unroll
    for (int j = 0; j < 8; j++) acc[i][j] = 0.f;

  for (int k0 = 0; k0 < K; k0 += 16) {
    float4 a0 = *(const float4*)&A[(size_t)(bm+am)*lda + k0 + akq];
    float4 a1 = *(const float4*)&A[(size_t)(bm+am)*lda + k0 + akq + 4];
    float4 b0 = *(const float4*)&Bb[(size_t)(k0+bk)*ldb + bn + bj];
    float4 b1 = *(const float4*)&Bb[(size_t)(k0+bk+8)*ldb + bn + bj];
    As[akq+0][am] = a0.x; As[akq+1][am] = a0.y; As[akq+2][am] = a0.z; As[akq+3][am] = a0.w;
    As[akq+4][am] = a1.x; As[akq+5][am] = a1.y; As[akq+6][am] = a1.z; As[akq+7][am] = a1.w;
    *(float4*)&Bs[bk][bj] = b0;
    *(float4*)&Bs[bk+8][bj] = b1;
    __syncthreads();
    #pragma unroll
    for (int k = 0; k < 16; k++) {
      float av[8], bv[8];
      float4 x0 = *(const float4*)&As[k][tx*4];
      float4 x1 = *(const float4*)&As[k][tx*4+64];
      float4 y0 = *(const float4*)&Bs[k][ty*4];
      float4 y1 = *(const float4*)&Bs[k][ty*4+64];
      av[0]=x0.x; av[1]=x0.y; av[2]=x0.z; av[3]=x0.w;
      av[4]=x1.x; av[5]=x1.y; av[6]=x1.z; av[7]=x1.w;
      bv[0]=y0.x; bv[1]=y0.y; bv[2]=y0.z; bv[3]=y0.w;
      bv[4]=y1.x; bv[5]=y1.y; bv[6]=y1.z; bv[7]=y1.w;
      #pragma unroll
      for (int i = 0; i < 8; i++)
        #pragma unroll
        for (int j = 0; j < 8; j++)
          acc[i][j] += av[i] * bv[j];
    }
    __syncthreads();
  }

  #pragma unroll
  for (int i = 0; i < 8; i++) {
    int mm = bm + ((i < 4) ? tx*4 + i : 64 + tx*4 + (i-4));
    float bia = BIAS ? bias[mm] : 0.f;
    float4 v0 = make_float4(acc[i][0]+bia, acc[i][1]+bia, acc[i][2]+bia, acc[i][3]+bia);
    float4 v1 = make_float4(acc[i][4]+bia, acc[i][5]+bia, acc[i][6]+bia, acc[i][7]+bia);
    *(float4*)&Cb[(size_t)mm*ldc + bn + ty*4]      = v0;
    *(float4*)&Cb[(size_t)mm*ldc + bn + 64 + ty*4] = v1;
  }
}

// ---------------- fused z_e GEMM + rownorm + enc split, direct-z staging ----
// Replaces the old split_z + ze_enc pair: the A-operand (z, [b][d][t] fp32) is
// transpose-convert-staged IN-KERNEL. Per K-step, thread (dl,tg) loads 8
// consecutive fp32 along t from row d=it*32+dl (coalesced: 16 lanes cover a
// full 512B row segment), converts to bf16 hi/lo with the SAME bf16_rne math
// as the old split_z (bitwise-identical MFMA inputs), and scatter-writes them
// into the SAME swizzled LDS layout the fragment reader expects:
//   byte = t*64 + ((d>>3) ^ swz4(t))*16 + (d&7)*2.
// T14 async split: fp32 loads for it+1 issued at top of step it; convert +
// ds_write placed AFTER the MFMA cluster (HBM latency hidden under MFMA).
// One barrier per K-step publishes both A (ds_write, lgkmcnt) and B
// (global_load_lds, vmcnt) buffers. MFMA order unchanged.
__global__ __launch_bounds__(512) void k_ze_enc(
    const float* __restrict__ z,
    const ushort_t* __restrict__ wh, const ushort_t* __restrict__ wl,
    const float* __restrict__ in_b,
    ushort_t* __restrict__ ehi, ushort_t* __restrict__ elo,
    float* __restrict__ inv, float* __restrict__ enc2, float* __restrict__ e2raw)
{
  __shared__ ushort_t smem[49152];     // 96KB: Ah[2][4096] Al[2][4096] Bh[2][8192] Bl[2][8192]
  __shared__ float e2s[128][4];
  __shared__ float sIv[128];

  ushort_t* sAh = smem;
  ushort_t* sAl = smem + 8192;
  ushort_t* sBh = smem + 16384;
  ushort_t* sBl = smem + 32768;

  const int t0 = blockIdx.x * 128;
  const int b  = blockIdx.y;
  const int tid = threadIdx.x;
  const int lane = tid & 63;
  const int wave = tid >> 6;
  const int wr = wave >> 2, wc = wave & 3;      // 2x4 wave grid
  const int ml = lane & 15, quad = lane >> 4;
  const size_t r0 = (size_t)b*TT + t0;

  // A transpose staging: thread (dl 0..31, tg 0..15)
  const int dl = tid >> 4, tg = tid & 15;
  const float* zsrc = z + (size_t)b*DIN*TT + (size_t)dl*TT + t0 + tg*8;
  int idxA[8];
  #pragma unroll
  for (int i = 0; i < 8; i++) {
    int t = tg*8 + i;
    idxA[i] = t*32 + (((dl >> 3) ^ swz4(t)) << 3) + (dl & 7);
  }

  // B staging: 1024 chunks (256 rows x 32k), 2 per thread
  int goB[2];
  #pragma unroll
  for (int l = 0; l < 2; l++) {
    int chunk = l*512 + tid;
    int r = chunk >> 2, c = chunk & 3;
    int g = c ^ swz4(r);
    goB[l] = r*DIN + (g << 3);
  }
  const int wu = wave * 512;

  int offA[4], offB[4];
  #pragma unroll
  for (int i = 0; i < 4; i++) {
    int r = wr*64 + i*16 + ml;
    int p = quad ^ swz4(r);
    offA[i] = r*64 + p*16;
  }
  #pragma unroll
  for (int i = 0; i < 4; i++) {
    int r = wc*64 + i*16 + ml;
    int p = quad ^ swz4(r);
    offB[i] = r*64 + p*16;
  }

  f32x4 acc[4][4];
  #pragma unroll
  for (int i = 0; i < 4; i++)
    #pragma unroll
    for (int j = 0; j < 4; j++) acc[i][j] = (f32x4)0.f;

  // prologue: K-step 0 into buf 0
  float4 va = *(const float4*)(zsrc);
  float4 vb = *(const float4*)(zsrc + 4);
  stage2(wh, sBh, goB, wu);
  stage2(wl, sBl, goB, wu);
  {
    float vv[8] = {va.x, va.y, va.z, va.w, vb.x, vb.y, vb.z, vb.w};
    #pragma unroll
    for (int i = 0; i < 8; i++) {
      ushort_t h = bf16_rne(vv[i]);
      sAh[idxA[i]] = h;
      sAl[idxA[i]] = bf16_rne(vv[i] - bf16f(h));
    }
  }

  for (int it = 0; it < 32; ++it) {
    __syncthreads();                           // publishes A (lgkm) + B (vmcnt) of buf[it&1]
    const int cbuf = it & 1, nb = cbuf ^ 1;
    if (it < 31) {
      va = *(const float4*)(zsrc + (size_t)(it+1)*32*TT);
      vb = *(const float4*)(zsrc + (size_t)(it+1)*32*TT + 4);
      stage2(wh + (it+1)*32, sBh + nb*8192, goB, wu);
      stage2(wl + (it+1)*32, sBl + nb*8192, goB, wu);
    }
    const char* pAh = (const char*)(sAh + cbuf*4096);
    const char* pAl = (const char*)(sAl + cbuf*4096);
    const char* pBh = (const char*)(sBh + cbuf*8192);
    const char* pBl = (const char*)(sBl + cbuf*8192);

    short8 fbh[4], fbl[4];
    #pragma unroll
    for (int ci = 0; ci < 4; ci++) {
      fbh[ci] = LD8(pBh, offB[ci]);
      fbl[ci] = LD8(pBl, offB[ci]);
    }
    #pragma unroll
    for (int ri = 0; ri < 4; ri++) {
      short8 ah = LD8(pAh, offA[ri]);
      short8 al = LD8(pAl, offA[ri]);
      #pragma unroll
      for (int ci = 0; ci < 4; ci++) {
        acc[ri][ci] = __builtin_amdgcn_mfma_f32_16x16x32_bf16(ah, fbh[ci], acc[ri][ci], 0, 0, 0);
        acc[ri][ci] = __builtin_amdgcn_mfma_f32_16x16x32_bf16(al, fbh[ci], acc[ri][ci], 0, 0, 0);
        acc[ri][ci] = __builtin_amdgcn_mfma_f32_16x16x32_bf16(ah, fbl[ci], acc[ri][ci], 0, 0, 0);
      }
    }

    if (it < 31) {
      // convert + scatter-write A(it+1) into buf[nb]; buf[nb] reads retired
      // at this step's entry barrier. HBM latency of va/vb hidden by MFMA.
      ushort_t* dAh = sAh + nb*4096;
      ushort_t* dAl = sAl + nb*4096;
      float vv[8] = {va.x, va.y, va.z, va.w, vb.x, vb.y, vb.z, vb.w};
      #pragma unroll
      for (int i = 0; i < 8; i++) {
        ushort_t h = bf16_rne(vv[i]);
        dAh[idxA[i]] = h;
        dAl[idxA[i]] = bf16_rne(vv[i] - bf16f(h));
      }
    }
  }

  // ---- add bias; per-t e2 partials (deterministic: shfl tree + fixed slots) ----
  float bia[4];
  #pragma unroll
  for (int ci = 0; ci < 4; ci++) bia[ci] = in_b[wc*64 + ci*16 + ml];

  #pragma unroll
  for (int ri = 0; ri < 4; ri++) {
    #pragma unroll
    for (int reg = 0; reg < 4; reg++) {
      float p = 0.f;
      #pragma unroll
      for (int ci = 0; ci < 4; ci++) {
        float v = acc[ri][ci][reg] + bia[ci];
        acc[ri][ci][reg] = v;
        p += v*v;
      }
      #pragma unroll
      for (int off = 1; off < 16; off <<= 1) p += __shfl_xor(p, off);
      if (ml == 0) e2s[wr*64 + ri*16 + quad*4 + reg][wc] = p;
    }
  }
  __syncthreads();
  if (tid < 128) {
    float s = ((e2s[tid][0] + e2s[tid][1]) + e2s[tid][2]) + e2s[tid][3];
    float iv = 1.f / fmaxf(sqrtf(s), EPSF);
    sIv[tid] = iv;
    inv[r0 + tid]   = iv;
    enc2[r0 + tid]  = (s * iv) * iv;
    e2raw[r0 + tid] = s;
  }
  __syncthreads();

  // ---- enc write via LDS transpose bounce (2 passes: hi then lo) ----
  ushort_t* tb = smem;                          // reuse staging as [128][256]
  #pragma unroll
  for (int ri = 0; ri < 4; ri++) {
    #pragma unroll
    for (int reg = 0; reg < 4; reg++) {
      int t_loc = wr*64 + ri*16 + quad*4 + reg;
      float ivt = sIv[t_loc];
      #pragma unroll
      for (int ci = 0; ci < 4; ci++) {
        int c_loc = wc*64 + ci*16 + ml;
        tb[t_loc*256 + c_loc] = bf16_rne(acc[ri][ci][reg] * ivt);
      }
    }
  }
  __syncthreads();
  #pragma unroll
  for (int p = 0; p < 8; p++) {
    int ch = p*512 + tid;
    *(short8*)(ehi + r0*DC + (size_t)ch*8) = *(const short8*)(tb + ch*8);
  }
  __syncthreads();
  #pragma unroll
  for (int ri = 0; ri < 4; ri++) {
    #pragma unroll
    for (int reg = 0; reg < 4; reg++) {
      int t_loc = wr*64 + ri*16 + quad*4 + reg;
      float ivt = sIv[t_loc];
      #pragma unroll
      for (int ci = 0; ci < 4; ci++) {
        int c_loc = wc*64 + ci*16 + ml;
        float v = acc[ri][ci][reg] * ivt;
        ushort_t h = bf16_rne(v);
        tb[t_loc*256 + c_loc] = bf16_rne(v - bf16f(h));
      }
    }
  }
  __syncthreads();
  #pragma unroll
  for (int p = 0; p < 8; p++) {
    int ch = p*512 + tid;
    *(short8*)(elo + r0*DC + (size_t)ch*8) = *(const short8*)(tb + ch*8);
  }
}

// ---------------- W2T via split-bf16 MFMA ----------------
__global__ __launch_bounds__(256) void k_w2t_mfma(
    const ushort_t* __restrict__ ah_g, const ushort_t* __restrict__ al_g,
    const ushort_t* __restrict__ bh_g, const ushort_t* __restrict__ bl_g,
    float* __restrict__ C)
{
  __shared__ ushort_t As_hi[2][4096];
  __shared__ ushort_t As_lo[2][4096];
  __shared__ ushort_t Bs_hi[2][4096];
  __shared__ ushort_t Bs_lo[2][4096];

  const int m0 = blockIdx.x * 128;
  const int n0 = blockIdx.y * 128;
  const int tid = threadIdx.x;
  const int lane = tid & 63;
  const int wave = tid >> 6;
  const int wr = wave >> 1, wc = wave & 1;
  const int m = lane & 15, quad = lane >> 4;

  const ushort_t* src; ushort_t* dst;
  {
    size_t aoff = (size_t)m0 * DC;
    size_t boff = (size_t)n0 * DC;
    if      (wave == 0) { src = ah_g + aoff; dst = &As_hi[0][0]; }
    else if (wave == 1) { src = al_g + aoff; dst = &As_lo[0][0]; }
    else if (wave == 2) { src = bh_g + boff; dst = &Bs_hi[0][0]; }
    else                { src = bl_g + boff; dst = &Bs_lo[0][0]; }
  }
  const int rr = lane >> 2, cc = lane & 3;

  int goT[8];
  #pragma unroll
  for (int i = 0; i < 8; i++) {
    int r = i*16 + rr;
    int g = cc ^ swz4(r);
    goT[i] = r*DC + (g << 3);
  }

  int offA[4], offB[4];
  #pragma unroll
  for (int ri = 0; ri < 4; ri++) {
    int r = wr*64 + ri*16 + m;
    int p = quad ^ swz4(r);
    offA[ri] = r*64 + p*16;
  }
  #pragma unroll
  for (int ci = 0; ci < 4; ci++) {
    int r = wc*64 + ci*16 + m;
    int p = quad ^ swz4(r);
    offB[ci] = r*64 + p*16;
  }

  f32x4 acc[4][4];
  #pragma unroll
  for (int i = 0; i < 4; i++)
    #pragma unroll
    for (int j = 0; j < 4; j++) acc[i][j] = (f32x4)0.f;

  stage_tile8(src, dst, goT);

  for (int it = 0; it < 8; ++it) {
    __syncthreads();
    if (it < 7) stage_tile8(src + (it+1)*32, dst + ((it+1)&1)*4096, goT);
    const int bo = (it & 1) << 13;

    short8 bh[4], bl[4];
    #pragma unroll
    for (int ci = 0; ci < 4; ci++) {
      bh[ci] = *(const short8*)((const char*)Bs_hi + bo + offB[ci]);
      bl[ci] = *(const short8*)((const char*)Bs_lo + bo + offB[ci]);
    }
    #pragma unroll
    for (int ri = 0; ri < 4; ri++) {
      short8 ah = *(const short8*)((const char*)As_hi + bo + offA[ri]);
      short8 al = *(const short8*)((const char*)As_lo + bo + offA[ri]);
      #pragma unroll
      for (int ci = 0; ci < 4; ci++) {
        acc[ri][ci] = __builtin_amdgcn_mfma_f32_16x16x32_bf16(ah, bh[ci], acc[ri][ci], 0, 0, 0);
        acc[ri][ci] = __builtin_amdgcn_mfma_f32_16x16x32_bf16(al, bh[ci], acc[ri][ci], 0, 0, 0);
        acc[ri][ci] = __builtin_amdgcn_mfma_f32_16x16x32_bf16(ah, bl[ci], acc[ri][ci], 0, 0, 0);
      }
    }
  }

  #pragma unroll
  for (int ri = 0; ri < 4; ri++) {
    int m_loc = wr*64 + ri*16 + quad*4;
    #pragma unroll
    for (int ci = 0; ci < 4; ci++) {
      int n_loc = wc*64 + ci*16 + m;
      #pragma unroll
      for (int reg = 0; reg < 4; reg++) {
        C[(size_t)(m0 + m_loc + reg)*DIN + n0 + n_loc] = acc[ri][ci][reg];
      }
    }
  }
}

// ---------------- fallback-only: column norms + enc split + loss ----------------
__global__ void k_colnorm(const float* __restrict__ ze, float* __restrict__ inv,
                          float* __restrict__ enc2) {
  int r = blockIdx.x * 128 + threadIdx.x;
  int b = r >> 12, t = r & 4095;
  const float* p = ze + (size_t)b*DC*TT + t;
  float s = 0.f;
  for (int c = 0; c < DC; c++) { float x = p[(size_t)c*TT]; s += x*x; }
  float iv = 1.f / fmaxf(sqrtf(s), EPSF);
  inv[r] = iv;
  enc2[r] = (s * iv) * iv;
}

__global__ void k_split_enc(const float* __restrict__ ze, const float* __restrict__ inv,
                            ushort_t* __restrict__ ehi, ushort_t* __restrict__ elo) {
  __shared__ float tile[64][65];
  int b = blockIdx.z, t0 = blockIdx.x * 64, c0 = blockIdx.y * 64;
  int tx = threadIdx.x & 63, ty = threadIdx.x >> 6;
  const float* zb = ze + (size_t)b*DC*TT;
  #pragma unroll
  for (int i = 0; i < 16; i++) {
    int c = i*4 + ty;
    tile[c][tx] = zb[(size_t)(c0+c)*TT + t0 + tx];
  }
  __syncthreads();
  #pragma unroll
  for (int i = 0; i < 16; i++) {
    int t = i*4 + ty;
    float iv = inv[b*TT + t0 + t];
    float val = tile[tx][t] * iv;
    ushort_t h = bf16_rne(val);
    size_t o = ((size_t)(b*TT + t0 + t))*DC + c0 + tx;
    ehi[o] = h;
    elo[o] = bf16_rne(val - bf16f(h));
  }
}

__global__ void k_lossidx(const float* __restrict__ ze, const float* __restrict__ cb,
                          const unsigned long long* __restrict__ keys,
                          float* __restrict__ loss_sums, float* __restrict__ out_idx)
{
  __shared__ float sb[4];
  __shared__ int sj[64];
  int b = blockIdx.y, t0 = blockIdx.x * 64;
  int tid = threadIdx.x;
  if (tid < 64) {
    unsigned long long k = keys[(size_t)b*TT + t0 + tid];
    int j = (int)(unsigned)(k & 0xFFFFFFFFull);
    sj[tid] = j;
    out_idx[(size_t)b*TT + t0 + tid] = (float)j;
  }
  __syncthreads();
  int tt = tid & 63, tc = tid >> 6;
  const float* zb = ze + (size_t)b*DC*TT + t0;
  int j = sj[tt];
  float s = 0.f;
  for (int ci = 0; ci < 64; ci++) {
    int c = tc + ci*4;
    float zev = zb[(size_t)c*TT + tt];
    float zqv = cb[(size_t)j*DC + c];
    float d = zev - zqv;
    s += d*d;
  }
  s = block_reduce_sum_256(s, sb);
  if (tid == 0) atomicAdd(&loss_sums[b], s);
}

// ---------------- fused distance + argmin (R3-proven structure) ----------------
__global__ __launch_bounds__(512, 2) void k_dist_mfma(
    const ushort_t* __restrict__ ehi, const ushort_t* __restrict__ elo,
    const ushort_t* __restrict__ cbh, const ushort_t* __restrict__ cbl,
    const float* __restrict__ nrm2, const float* __restrict__ enc2,
    unsigned long long* __restrict__ keys)
{
  __shared__ ushort_t sAh[2][8192];
  __shared__ ushort_t sAl[2][8192];
  __shared__ ushort_t sBh[2][8192];
  __shared__ ushort_t sBl[2][8192];
  __shared__ float sE2[256], sN2[256];
  __shared__ unsigned long long rkey[256];

  const int j0 = blockIdx.x * 256;
  const size_t r0 = (size_t)blockIdx.y * 256;
  const int tid = threadIdx.x;
  const int lane = tid & 63;
  const int wave = tid >> 6;
  const int wr = wave >> 2, wc = wave & 3;
  const int ml = lane & 15, quad = lane >> 4;

  if (tid < 256) {
    sE2[tid] = enc2[r0 + tid];
    sN2[tid] = nrm2[j0 + tid];
    rkey[tid] = 0xFFFFFFFFFFFFFFFFull;
  }

  const ushort_t* gAh = ehi + r0 * DC;
  const ushort_t* gAl = elo + r0 * DC;
  const ushort_t* gBh = cbh + (size_t)j0 * DC;
  const ushort_t* gBl = cbl + (size_t)j0 * DC;

  int goS[2];
  #pragma unroll
  for (int l = 0; l < 2; l++) {
    int chunk = l*512 + tid;
    int r = chunk >> 2, c = chunk & 3;
    int g = c ^ swz4(r);
    goS[l] = r*DC + (g << 3);
  }
  const int wu = wave * 512;

  int offA[8], offB[4];
  #pragma unroll
  for (int i = 0; i < 8; i++) {
    int r = wr*128 + i*16 + ml;
    int p = quad ^ swz4(r);
    offA[i] = r*64 + p*16;
  }
  #pragma unroll
  for (int i = 0; i < 4; i++) {
    int r = wc*64 + i*16 + ml;
    int p = quad ^ swz4(r);
    offB[i] = r*64 + p*16;
  }

  f32x4 acc[8][4];
  #pragma unroll
  for (int i = 0; i < 8; i++)
    #pragma unroll
    for (int j = 0; j < 4; j++) acc[i][j] = (f32x4)0.f;

  stage2(gBh,      &sBh[0][0], goS, wu);
  stage2(gBl,      &sBl[0][0], goS, wu);
  stage2(gAh,      &sAh[0][0], goS, wu);
  stage2(gAl,      &sAl[0][0], goS, wu);
  stage2(gBh + 32, &sBh[1][0], goS, wu);
  stage2(gBl + 32, &sBl[1][0], goS, wu);
  asm volatile("s_waitcnt vmcnt(4)" ::: "memory");
  asm volatile("s_waitcnt lgkmcnt(0)" ::: "memory");
  __builtin_amdgcn_s_barrier();
  __builtin_amdgcn_sched_barrier(0);

  short8 fa_h[4], fa_l[4], fb_h[4], fb_l[4];

  #pragma unroll 2
  for (int k = 0; k < 8; k++) {
    const int cb = k & 1, nb = cb ^ 1;
    const char* pAh = (const char*)&sAh[cb][0];
    const char* pAl = (const char*)&sAl[cb][0];
    const char* pBh = (const char*)&sBh[cb][0];
    const char* pBl = (const char*)&sBl[cb][0];
    __builtin_amdgcn_sched_barrier(0);

    #pragma unroll
    for (int i = 0; i < 4; i++) { fa_h[i] = LD8(pAh, offA[i]); fa_l[i] = LD8(pAl, offA[i]); }
    #pragma unroll
    for (int i = 0; i < 2; i++) { fb_h[i] = LD8(pBh, offB[i]); fb_l[i] = LD8(pBl, offB[i]); }
    if (k < 7) stage2(gAh + (size_t)(k+1)*32, &sAh[nb][0], goS, wu);
    __builtin_amdgcn_s_barrier();
    __builtin_amdgcn_s_setprio(1);
    qmfma<0, 0>(acc, fa_h, fa_l, fb_h, fb_l);
    __builtin_amdgcn_s_setprio(0);
    __builtin_amdgcn_s_barrier();

    #pragma unroll
    for (int i = 2; i < 4; i++) { fb_h[i] = LD8(pBh, offB[i]); fb_l[i] = LD8(pBl, offB[i]); }
    if (k < 7) stage2(gAl + (size_t)(k+1)*32, &sAl[nb][0], goS, wu);
    __builtin_amdgcn_s_barrier();
    __builtin_amdgcn_s_setprio(1);
    qmfma<0, 2>(acc, fa_h, fa_l, fb_h, fb_l);
    __builtin_amdgcn_s_setprio(0);
    __builtin_amdgcn_s_barrier();

    #pragma unroll
    for (int i = 0; i < 4; i++) { fa_h[i] = LD8(pAh, offA[4+i]); fa_l[i] = LD8(pAl, offA[4+i]); }
    if (k < 6) {
      stage2(gBh + (size_t)(k+2)*32, &sBh[cb][0], goS, wu);
      stage2(gBl + (size_t)(k+2)*32, &sBl[cb][0], goS, wu);
    }
    __builtin_amdgcn_s_barrier();
    __builtin_amdgcn_s_setprio(1);
    qmfma<1, 2>(acc, fa_h, fa_l, fb_h, fb_l);
    qmfma<1, 0>(acc, fa_h, fa_l, fb_h, fb_l);
    __builtin_amdgcn_s_setprio(0);
    if (k < 6) { asm volatile("s_waitcnt vmcnt(4)" ::: "memory"); }
    else       { asm volatile("s_waitcnt vmcnt(0)" ::: "memory"); }
    __builtin_amdgcn_s_barrier();
  }

  #pragma unroll
  for (int ri = 0; ri < 8; ri++) {
    #pragma unroll
    for (int reg = 0; reg < 4; reg++) {
      int t_loc = wr*128 + ri*16 + quad*4 + reg;
      float e2 = sE2[t_loc];
      unsigned long long best = 0xFFFFFFFFFFFFFFFFull;
      #pragma unroll
      for (int ci = 0; ci < 4; ci++) {
        int j_loc = wc*64 + ci*16 + ml;
        float d = e2 - 2.0f * acc[ri][ci][reg];
        d = d + sN2[j_loc];
        unsigned long long key =
            ((unsigned long long)__float_as_uint(d) << 32) | (unsigned)(j0 + j_loc);
        best = key < best ? key : best;
      }
      #pragma unroll
      for (int off = 1; off < 16; off <<= 1) {
        unsigned long long o = __shfl_xor(best, off);
        best = o < best ? o : best;
      }
      if (ml == 0) atomicMin(&rkey[t_loc], best);
    }
  }
  __syncthreads();
  if (tid < 256) atomicMin(&keys[r0 + tid], rkey[tid]);
}

// ---------------- loss reconstruction (no z_e needed) ----------------
__global__ void k_lossrec(const unsigned long long* __restrict__ keys,
                          const float* __restrict__ enc2, const float* __restrict__ nrm2,
                          const float* __restrict__ e2raw, const float* __restrict__ inv,
                          const float* __restrict__ nmraw, const float* __restrict__ n2raw,
                          float* __restrict__ loss_sums, float* __restrict__ out_idx)
{
  __shared__ float sb[4];
  int r = blockIdx.x * 256 + threadIdx.x;
  int b = r >> 12;
  unsigned long long k = keys[r];
  int j = (int)(unsigned)(k & 0xFFFFFFFFull);
  float d = __uint_as_float((unsigned)(k >> 32));
  out_idx[r] = (float)j;
  float dotn = 0.5f * (enc2[r] + nrm2[j] - d);
  float dot_raw = nmraw[j] * dotn / inv[r];
  float le = e2raw[r] - 2.f*dot_raw + n2raw[j];
  float s = block_reduce_sum_256(le, sb);
  if (threadIdx.x == 0) atomicAdd(&loss_sums[b], s);
}

__global__ void k_losswrite(const float* __restrict__ loss_sums, float* __restrict__ out_loss) {
  int i = threadIdx.x;
  if (i < 8) {
    float v = loss_sums[i] * (1.f/1048576.f);
    out_loss[i] = v;
    out_loss[8 + i] = v;
  }
}

// ---------------- output gather ----------------
__global__ void k_outgather(const float* __restrict__ W2T,
                            const unsigned long long* __restrict__ keys,
                            const float* __restrict__ out_b, float* __restrict__ out)
{
  __shared__ float tile[64][65];
  __shared__ int sj[64];
  int b = blockIdx.y, t0 = blockIdx.x * 64;
  int tid = threadIdx.x;
  if (tid < 64) sj[tid] = (int)(unsigned)(keys[(size_t)b*TT + t0 + tid] & 0xFFFFFFFFull);
  __syncthreads();
  float* ob = out + (size_t)b*DIN*TT;
  int dd = tid & 63, tq = tid >> 6;
  for (int d0 = 0; d0 < DIN; d0 += 64) {
    #pragma unroll
    for (int i = 0; i < 16; i++) {
      int t = tq*16 + i;
      tile[t][dd] = W2T[(size_t)sj[t]*DIN + d0 + dd];
    }
    __syncthreads();
    #pragma unroll
    for (int i = 0; i < 16; i++) {
      int d = tq*16 + i;
      ob[(size_t)(d0+d)*TT + t0 + dd] = tile[dd][d] + out_b[d0+d];
    }
    __syncthreads();
  }
}

// ---------------- launch ----------------
extern "C" void kernel_launch(void* const* d_in, const int* in_sizes, int n_in,
                              void* d_out, int out_size, void* d_ws, size_t ws_size,
                              hipStream_t stream) {
  const float* z        = (const float*)d_in[0];
  const float* in_v     = (const float*)d_in[1];
  const float* in_g     = (const float*)d_in[2];
  const float* in_b     = (const float*)d_in[3];
  const float* out_v    = (const float*)d_in[4];
  const float* out_g    = (const float*)d_in[5];
  const float* out_b    = (const float*)d_in[6];
  const float* codebook = (const float*)d_in[7];

  char* w = (char*)d_ws;
  float* w_in   = (float*)(w + OFF_WIN);
  float* w_outT = (float*)(w + OFF_WOUTT);               // fallback only
  float* e2raw  = (float*)(w + OFF_WOUTT);               // mfma only (aliases w_outT)
  float* nmraw  = (float*)(w + OFF_WOUTT + 131072);
  float* n2raw  = (float*)(w + OFF_WOUTT + 163840);
  ushort_t* cb_hi = (ushort_t*)(w + OFF_CBN);
  ushort_t* cb_lo = cb_hi + (size_t)CS*DC;
  float* nrm2   = (float*)(w + OFF_NRM2);
  float* z_e    = (float*)(w + OFF_ZE);                  // fallback only
  ushort_t* enc_hi_m = (ushort_t*)(w + OFF_ZE);          // mfma only (aliases z_e)
  ushort_t* enc_lo_m = enc_hi_m + (size_t)BB*TT*DC;
  float* inv    = (float*)(w + OFF_INV);
  float* enc2   = (float*)(w + OFF_ENC2);
  unsigned long long* keys = (unsigned long long*)(w + OFF_KEYS);
  float* loss_sums = (float*)(w + OFF_LOSS);
  ushort_t* w_hi = (ushort_t*)(w + OFF_WSPL);
  ushort_t* w_lo = w_hi + (size_t)DC*DIN;
  // OFF_W2T region: W2T (33.6MB) | cbr split (8.4MB) | wout split (1MB).
  ushort_t* enc_hi_fb = (ushort_t*)(w + OFF_W2T);        // fallback enc location
  ushort_t* enc_lo_fb = enc_hi_fb + (size_t)BB*TT*DC;
  float* W2T    = (float*)(w + OFF_W2T);
  ushort_t* cbr_hi  = (ushort_t*)(w + OFF_W2T + 33554432);
  ushort_t* cbr_lo  = cbr_hi + (size_t)CS*DC;
  ushort_t* wout_hi = (ushort_t*)(w + OFF_W2T + 33554432 + 8388608);
  ushort_t* wout_lo = wout_hi + (size_t)DIN*DC;

  float* out      = (float*)d_out;
  float* out_loss = out + (size_t)BB*DIN*TT;
  float* out_idx  = out_loss + 16;

  hipMemsetAsync(keys, 0xFF, 32768ull*8, stream);
  hipMemsetAsync(loss_sums, 0, 32, stream);

  const bool mfma_path = (ws_size >= REQ_WS_ZE);

  k_prep_win <<<256, 256, 0, stream>>>(in_v, in_g, w_in, w_hi, w_lo);
  k_prep_cb  <<<8192, 256, 0, stream>>>(codebook, cb_hi, cb_lo, nrm2, nmraw, n2raw,
                                        cbr_hi, cbr_lo);

  if (mfma_path) {
    k_split_wout<<<1024, 256, 0, stream>>>(out_v, out_g, wout_hi, wout_lo);

    k_ze_enc<<<dim3(32, 8), 512, 0, stream>>>(
        z, w_hi, w_lo, in_b, enc_hi_m, enc_lo_m, inv, enc2, e2raw);

    k_dist_mfma<<<dim3(32, 128), 512, 0, stream>>>(
        enc_hi_m, enc_lo_m, cb_hi, cb_lo, nrm2, enc2, keys);

    k_lossrec<<<128, 256, 0, stream>>>(
        keys, enc2, nrm2, e2raw, inv, nmraw, n2raw, loss_sums, out_idx);
    k_losswrite<<<1, 64, 0, stream>>>(loss_sums, out_loss);

    k_w2t_mfma<<<dim3(64, 8), 256, 0, stream>>>(cbr_hi, cbr_lo, wout_hi, wout_lo, W2T);
  } else {
    k_prep_wout<<<1024, 256, 0, stream>>>(out_v, out_g, w_outT);
    k_gemm<true><<<dim3(32, 2, 8), 256, 0, stream>>>(
        w_in, z, in_b, z_e, 1024, 1024, 4096, 4096,
        (size_t)DIN*TT, (size_t)DC*TT);
    k_colnorm<<<256, 128, 0, stream>>>(z_e, inv, enc2);
    k_split_enc<<<dim3(64, 4, 8), 256, 0, stream>>>(z_e, inv, enc_hi_fb, enc_lo_fb);

    k_dist_mfma<<<dim3(32, 128), 512, 0, stream>>>(
        enc_hi_fb, enc_lo_fb, cb_hi, cb_lo, nrm2, enc2, keys);

    k_lossidx<<<dim3(64, 8), 256, 0, stream>>>(z_e, codebook, keys, loss_sums, out_idx);
    k_losswrite<<<1, 64, 0, stream>>>(loss_sums, out_loss);

    k_gemm<false><<<dim3(8, 64, 1), 256, 0, stream>>>(
        codebook, w_outT, nullptr, W2T, 256, 256, 1024, 1024,
        (size_t)0, (size_t)0);
  }

  k_outgather<<<dim3(64, 8), 256, 0, stream>>>(W2T, keys, out_b, out);
}

// Round 7
// 766.815 us; speedup vs baseline: 1.2809x; 1.0834x over previous
//
#include <hip/hip_runtime.h>
#include <stdint.h>

#define BB 8
#define TT 4096
#define DIN 1024
#define DC 256
#define CS 8192
#define EPSF 1e-12f

typedef unsigned short ushort_t;
typedef __attribute__((ext_vector_type(8))) short short8;
typedef __attribute__((ext_vector_type(4))) float f32x4;

// ---------------- workspace layout (bytes) ----------------
constexpr size_t OFF_WIN   = 0;                          // w_in fp32: 1MB (fallback gemm)
constexpr size_t OFF_WOUTT = OFF_WIN   + 1048576;        // fallback: w_outT 1MB | mfma: e2raw/nmraw/n2raw
constexpr size_t OFF_CBN   = OFF_WOUTT + 1048576;        // cb_hi/cb_lo bf16: 8.39MB
constexpr size_t OFF_NRM2  = OFF_CBN   + 8388608;        // nrm2: 32KB
constexpr size_t OFF_ZE    = OFF_NRM2  + 32768;          // fallback: z_e fp32 33.55MB | mfma: enc hi/lo 33.55MB
constexpr size_t OFF_INV   = OFF_ZE    + 33554432;       // inv: 128KB
constexpr size_t OFF_ENC2  = OFF_INV   + 131072;         // enc2: 128KB
constexpr size_t OFF_KEYS  = OFF_ENC2  + 131072;         // keys u64: 256KB
constexpr size_t OFF_LOSS  = OFF_KEYS  + 262144;         // loss: 256B
constexpr size_t OFF_WSPL  = OFF_LOSS  + 256;            // w_hi/w_lo bf16: 1MB
constexpr size_t OFF_W2T   = OFF_WSPL  + 1048576;        // W2T(33.6MB) + cbr(8.4MB) + wout(1MB) splits
constexpr size_t REQ_WS_ZE = OFF_W2T + 134217728ull;     // keep same threshold as prior rounds

// ---------------- helpers ----------------
__device__ __forceinline__ float block_reduce_sum_256(float v, float* sbuf) {
  #pragma unroll
  for (int o = 32; o > 0; o >>= 1) v += __shfl_down(v, o, 64);
  int lane = threadIdx.x & 63, w = threadIdx.x >> 6;
  if (lane == 0) sbuf[w] = v;
  __syncthreads();
  float r = sbuf[0] + sbuf[1] + sbuf[2] + sbuf[3];
  __syncthreads();
  return r;
}

__device__ __forceinline__ ushort_t bf16_rne(float x) {
  unsigned u = __float_as_uint(x);
  unsigned r = (u + 0x7FFFu + ((u >> 16) & 1u)) >> 16;
  return (ushort_t)r;
}
__device__ __forceinline__ float bf16f(ushort_t h) {
  return __uint_as_float(((unsigned)h) << 16);
}

// LDS chunk swizzle (proven config across all passing kernels).
// Invariant: LDS quad c of row r holds global 8-elem chunk c ^ swz4(r).
__device__ __forceinline__ int swz4(int r) {
  return (r + (r >> 2)) & 3;
}

__device__ __forceinline__ void async_copy16(const ushort_t* g, ushort_t* lds) {
  __builtin_amdgcn_global_load_lds(
      (const __attribute__((address_space(1))) void*)g,
      (__attribute__((address_space(3))) void*)lds, 16, 0, 0);
}

// stage one 128x32 bf16 tile (8KB) into LDS; per-wave; offsets precomputed.
__device__ __forceinline__ void stage_tile8(const ushort_t* __restrict__ s0,
                                            ushort_t* __restrict__ dstbuf,
                                            const int (&go)[8]) {
  #pragma unroll
  for (int i = 0; i < 8; i++) async_copy16(s0 + go[i], dstbuf + i*512);
}

// stage one 256x32 bf16 component tile (16KB) into LDS; 512 threads, 2 loads each.
__device__ __forceinline__ void stage2(const ushort_t* __restrict__ srcbase,
                                       ushort_t* __restrict__ comp,
                                       const int (&go)[2], int wu) {
  async_copy16(srcbase + go[0], comp + wu);
  async_copy16(srcbase + go[1], comp + wu + 4096);
}

#define LD8(base, off) (*(const short8*)((const char*)(base) + (off)))

// one C-quadrant of split-bf16 MFMA: rows MH*4..MH*4+3, cols CLO..CLO+1
template<int MH, int CLO>
__device__ __forceinline__ void qmfma(f32x4 (&acc)[8][4],
    const short8 (&fah)[4], const short8 (&fal)[4],
    const short8 (&fbh)[4], const short8 (&fbl)[4]) {
  #pragma unroll
  for (int r = 0; r < 4; r++) {
    #pragma unroll
    for (int c2 = 0; c2 < 2; c2++) {
      f32x4 t = acc[MH*4 + r][CLO + c2];
      t = __builtin_amdgcn_mfma_f32_16x16x32_bf16(fah[r], fbh[CLO + c2], t, 0, 0, 0);
      t = __builtin_amdgcn_mfma_f32_16x16x32_bf16(fal[r], fbh[CLO + c2], t, 0, 0, 0);
      t = __builtin_amdgcn_mfma_f32_16x16x32_bf16(fah[r], fbl[CLO + c2], t, 0, 0, 0);
      acc[MH*4 + r][CLO + c2] = t;
    }
  }
}

// ---------------- fused prep: w_in split | wout split | cb norms/splits ----
// grid 9472 x 256: [0,256) prep_win (+loss init), [256,1280) split_wout,
// [1280,9472) prep_cb (+keys init). Bodies identical to the proven separate
// kernels -> all derived values bitwise-unchanged.
__global__ void k_prep_all(
    const float* __restrict__ in_v, const float* __restrict__ in_g,
    float* __restrict__ w_in, ushort_t* __restrict__ wh, ushort_t* __restrict__ wl,
    const float* __restrict__ out_v, const float* __restrict__ out_g,
    ushort_t* __restrict__ wouth, ushort_t* __restrict__ woutl,
    const float* __restrict__ cb, ushort_t* __restrict__ cbh, ushort_t* __restrict__ cbl,
    float* __restrict__ nrm2, float* __restrict__ nmraw, float* __restrict__ n2raw,
    ushort_t* __restrict__ crh, ushort_t* __restrict__ crl,
    unsigned long long* __restrict__ keys, float* __restrict__ loss_sums)
{
  __shared__ float sb[4];
  const int bx = blockIdx.x, t = threadIdx.x;
  if (bx < 256) {
    // ---- prep_win ----
    if (bx == 0 && t < 8) loss_sums[t] = 0.f;
    int r = bx;
    float xv[4]; float s = 0.f;
    #pragma unroll
    for (int i = 0; i < 4; i++) { xv[i] = in_v[r*DIN + t + i*256]; s += xv[i]*xv[i]; }
    s = block_reduce_sum_256(s, sb);
    float sc = in_g[r] / fmaxf(sqrtf(s), EPSF);
    #pragma unroll
    for (int i = 0; i < 4; i++) {
      float val = xv[i] * sc;
      int idx = r*DIN + t + i*256;
      w_in[idx] = val;
      ushort_t h = bf16_rne(val);
      wh[idx] = h;
      wl[idx] = bf16_rne(val - bf16f(h));
    }
  } else if (bx < 1280) {
    // ---- split_wout ----
    int r = bx - 256;
    float x = out_v[r*DC + t];
    float s = block_reduce_sum_256(x*x, sb);
    float sc = out_g[r] / fmaxf(sqrtf(s), EPSF);
    float val = x * sc;
    ushort_t h = bf16_rne(val);
    wouth[r*DC + t] = h;
    woutl[r*DC + t] = bf16_rne(val - bf16f(h));
  } else {
    // ---- prep_cb (+ keys init) ----
    int j = bx - 1280;
    if (t < 4) keys[(size_t)j*4 + t] = 0xFFFFFFFFFFFFFFFFull;
    float x = cb[j*DC + t];
    ushort_t hr = bf16_rne(x);
    crh[j*DC + t] = hr;
    crl[j*DC + t] = bf16_rne(x - bf16f(hr));
    float s = block_reduce_sum_256(x*x, sb);
    float nm = fmaxf(sqrtf(s), EPSF);
    float cn = x / nm;
    ushort_t h = bf16_rne(cn);
    cbh[j*DC + t] = h;
    cbl[j*DC + t] = bf16_rne(cn - bf16f(h));
    float q = block_reduce_sum_256(cn*cn, sb);
    if (t == 0) { nrm2[j] = q; nmraw[j] = nm; n2raw[j] = s; }
  }
}

// ---------------- fallback-only prep kernels ----------------
__global__ void k_prep_win(const float* __restrict__ v, const float* __restrict__ g,
                           float* __restrict__ w, ushort_t* __restrict__ wh,
                           ushort_t* __restrict__ wl) {
  __shared__ float sb[4];
  int r = blockIdx.x, t = threadIdx.x;
  float xv[4]; float s = 0.f;
  #pragma unroll
  for (int i = 0; i < 4; i++) { xv[i] = v[r*DIN + t + i*256]; s += xv[i]*xv[i]; }
  s = block_reduce_sum_256(s, sb);
  float sc = g[r] / fmaxf(sqrtf(s), EPSF);
  #pragma unroll
  for (int i = 0; i < 4; i++) {
    float val = xv[i] * sc;
    int idx = r*DIN + t + i*256;
    w[idx] = val;
    ushort_t h = bf16_rne(val);
    wh[idx] = h;
    wl[idx] = bf16_rne(val - bf16f(h));
  }
}

__global__ void k_prep_wout(const float* __restrict__ v, const float* __restrict__ g,
                            float* __restrict__ wT) {
  __shared__ float sb[4];
  int r = blockIdx.x, t = threadIdx.x;
  float x = v[r*DC + t];
  float s = block_reduce_sum_256(x*x, sb);
  float sc = g[r] / fmaxf(sqrtf(s), EPSF);
  wT[t*DIN + r] = x * sc;
}

__global__ void k_prep_cb(const float* __restrict__ cb, ushort_t* __restrict__ cbh,
                          ushort_t* __restrict__ cbl, float* __restrict__ nrm2,
                          float* __restrict__ nmraw, float* __restrict__ n2raw,
                          ushort_t* __restrict__ crh, ushort_t* __restrict__ crl) {
  __shared__ float sb[4];
  int j = blockIdx.x, t = threadIdx.x;
  float x = cb[j*DC + t];
  ushort_t hr = bf16_rne(x);
  crh[j*DC + t] = hr;
  crl[j*DC + t] = bf16_rne(x - bf16f(hr));
  float s = block_reduce_sum_256(x*x, sb);
  float nm = fmaxf(sqrtf(s), EPSF);
  float cn = x / nm;
  ushort_t h = bf16_rne(cn);
  cbh[j*DC + t] = h;
  cbl[j*DC + t] = bf16_rne(cn - bf16f(h));
  float q = block_reduce_sum_256(cn*cn, sb);
  if (t == 0) { nrm2[j] = q; nmraw[j] = nm; n2raw[j] = s; }
}

// ---------------- fp32 GEMM (fallback path only) ----------------
template<bool BIAS>
__global__ __launch_bounds__(256) void k_gemm(
    const float* __restrict__ A, const float* __restrict__ Bmat,
    const float* __restrict__ bias, float* __restrict__ C,
    int K, int lda, int ldb, int ldc, size_t strideB, size_t strideC)
{
  __shared__ float As[16][132];
  __shared__ float Bs[16][132];
  const int bn = blockIdx.x * 128;
  const int bm = blockIdx.y * 128;
  const float* Bb = Bmat + (size_t)blockIdx.z * strideB;
  float* Cb = C + (size_t)blockIdx.z * strideC;
  const int tid = threadIdx.x;
  const int tx = tid & 15, ty = tid >> 4;
  const int am = tid & 127, akq = (tid >> 7) * 8;
  const int bk = tid >> 5, bj = (tid & 31) * 4;

  float acc[8][8];
  #pragma unroll
  for (int i = 0; i < 8; i++)
    #pragma unroll
    for (int j = 0; j < 8; j++) acc[i][j] = 0.f;

  for (int k0 = 0; k0 < K; k0 += 16) {
    float4 a0 = *(const float4*)&A[(size_t)(bm+am)*lda + k0 + akq];
    float4 a1 = *(const float4*)&A[(size_t)(bm+am)*lda + k0 + akq + 4];
    float4 b0 = *(const float4*)&Bb[(size_t)(k0+bk)*ldb + bn + bj];
    float4 b1 = *(const float4*)&Bb[(size_t)(k0+bk+8)*ldb + bn + bj];
    As[akq+0][am] = a0.x; As[akq+1][am] = a0.y; As[akq+2][am] = a0.z; As[akq+3][am] = a0.w;
    As[akq+4][am] = a1.x; As[akq+5][am] = a1.y; As[akq+6][am] = a1.z; As[akq+7][am] = a1.w;
    *(float4*)&Bs[bk][bj] = b0;
    *(float4*)&Bs[bk+8][bj] = b1;
    __syncthreads();
    #pragma unroll
    for (int k = 0; k < 16; k++) {
      float av[8], bv[8];
      float4 x0 = *(const float4*)&As[k][tx*4];
      float4 x1 = *(const float4*)&As[k][tx*4+64];
      float4 y0 = *(const float4*)&Bs[k][ty*4];
      float4 y1 = *(const float4*)&Bs[k][ty*4+64];
      av[0]=x0.x; av[1]=x0.y; av[2]=x0.z; av[3]=x0.w;
      av[4]=x1.x; av[5]=x1.y; av[6]=x1.z; av[7]=x1.w;
      bv[0]=y0.x; bv[1]=y0.y; bv[2]=y0.z; bv[3]=y0.w;
      bv[4]=y1.x; bv[5]=y1.y; bv[6]=y1.z; bv[7]=y1.w;
      #pragma unroll
      for (int i = 0; i < 8; i++)
        #pragma unroll
        for (int j = 0; j < 8; j++)
          acc[i][j] += av[i] * bv[j];
    }
    __syncthreads();
  }

  #pragma unroll
  for (int i = 0; i < 8; i++) {
    int mm = bm + ((i < 4) ? tx*4 + i : 64 + tx*4 + (i-4));
    float bia = BIAS ? bias[mm] : 0.f;
    float4 v0 = make_float4(acc[i][0]+bia, acc[i][1]+bia, acc[i][2]+bia, acc[i][3]+bia);
    float4 v1 = make_float4(acc[i][4]+bia, acc[i][5]+bia, acc[i][6]+bia, acc[i][7]+bia);
    *(float4*)&Cb[(size_t)mm*ldc + bn + ty*4]      = v0;
    *(float4*)&Cb[(size_t)mm*ldc + bn + 64 + ty*4] = v1;
  }
}

// ---------------- fused z_e GEMM + rownorm + enc split, direct-z staging ----
// (unchanged from R6 — proven)
__global__ __launch_bounds__(512) void k_ze_enc(
    const float* __restrict__ z,
    const ushort_t* __restrict__ wh, const ushort_t* __restrict__ wl,
    const float* __restrict__ in_b,
    ushort_t* __restrict__ ehi, ushort_t* __restrict__ elo,
    float* __restrict__ inv, float* __restrict__ enc2, float* __restrict__ e2raw)
{
  __shared__ ushort_t smem[49152];     // 96KB: Ah[2][4096] Al[2][4096] Bh[2][8192] Bl[2][8192]
  __shared__ float e2s[128][4];
  __shared__ float sIv[128];

  ushort_t* sAh = smem;
  ushort_t* sAl = smem + 8192;
  ushort_t* sBh = smem + 16384;
  ushort_t* sBl = smem + 32768;

  const int t0 = blockIdx.x * 128;
  const int b  = blockIdx.y;
  const int tid = threadIdx.x;
  const int lane = tid & 63;
  const int wave = tid >> 6;
  const int wr = wave >> 2, wc = wave & 3;      // 2x4 wave grid
  const int ml = lane & 15, quad = lane >> 4;
  const size_t r0 = (size_t)b*TT + t0;

  const int dl = tid >> 4, tg = tid & 15;
  const float* zsrc = z + (size_t)b*DIN*TT + (size_t)dl*TT + t0 + tg*8;
  int idxA[8];
  #pragma unroll
  for (int i = 0; i < 8; i++) {
    int t = tg*8 + i;
    idxA[i] = t*32 + (((dl >> 3) ^ swz4(t)) << 3) + (dl & 7);
  }

  int goB[2];
  #pragma unroll
  for (int l = 0; l < 2; l++) {
    int chunk = l*512 + tid;
    int r = chunk >> 2, c = chunk & 3;
    int g = c ^ swz4(r);
    goB[l] = r*DIN + (g << 3);
  }
  const int wu = wave * 512;

  int offA[4], offB[4];
  #pragma unroll
  for (int i = 0; i < 4; i++) {
    int r = wr*64 + i*16 + ml;
    int p = quad ^ swz4(r);
    offA[i] = r*64 + p*16;
  }
  #pragma unroll
  for (int i = 0; i < 4; i++) {
    int r = wc*64 + i*16 + ml;
    int p = quad ^ swz4(r);
    offB[i] = r*64 + p*16;
  }

  f32x4 acc[4][4];
  #pragma unroll
  for (int i = 0; i < 4; i++)
    #pragma unroll
    for (int j = 0; j < 4; j++) acc[i][j] = (f32x4)0.f;

  float4 va = *(const float4*)(zsrc);
  float4 vb = *(const float4*)(zsrc + 4);
  stage2(wh, sBh, goB, wu);
  stage2(wl, sBl, goB, wu);
  {
    float vv[8] = {va.x, va.y, va.z, va.w, vb.x, vb.y, vb.z, vb.w};
    #pragma unroll
    for (int i = 0; i < 8; i++) {
      ushort_t h = bf16_rne(vv[i]);
      sAh[idxA[i]] = h;
      sAl[idxA[i]] = bf16_rne(vv[i] - bf16f(h));
    }
  }

  for (int it = 0; it < 32; ++it) {
    __syncthreads();
    const int cbuf = it & 1, nb = cbuf ^ 1;
    if (it < 31) {
      va = *(const float4*)(zsrc + (size_t)(it+1)*32*TT);
      vb = *(const float4*)(zsrc + (size_t)(it+1)*32*TT + 4);
      stage2(wh + (it+1)*32, sBh + nb*8192, goB, wu);
      stage2(wl + (it+1)*32, sBl + nb*8192, goB, wu);
    }
    const char* pAh = (const char*)(sAh + cbuf*4096);
    const char* pAl = (const char*)(sAl + cbuf*4096);
    const char* pBh = (const char*)(sBh + cbuf*8192);
    const char* pBl = (const char*)(sBl + cbuf*8192);

    short8 fbh[4], fbl[4];
    #pragma unroll
    for (int ci = 0; ci < 4; ci++) {
      fbh[ci] = LD8(pBh, offB[ci]);
      fbl[ci] = LD8(pBl, offB[ci]);
    }
    #pragma unroll
    for (int ri = 0; ri < 4; ri++) {
      short8 ah = LD8(pAh, offA[ri]);
      short8 al = LD8(pAl, offA[ri]);
      #pragma unroll
      for (int ci = 0; ci < 4; ci++) {
        acc[ri][ci] = __builtin_amdgcn_mfma_f32_16x16x32_bf16(ah, fbh[ci], acc[ri][ci], 0, 0, 0);
        acc[ri][ci] = __builtin_amdgcn_mfma_f32_16x16x32_bf16(al, fbh[ci], acc[ri][ci], 0, 0, 0);
        acc[ri][ci] = __builtin_amdgcn_mfma_f32_16x16x32_bf16(ah, fbl[ci], acc[ri][ci], 0, 0, 0);
      }
    }

    if (it < 31) {
      ushort_t* dAh = sAh + nb*4096;
      ushort_t* dAl = sAl + nb*4096;
      float vv[8] = {va.x, va.y, va.z, va.w, vb.x, vb.y, vb.z, vb.w};
      #pragma unroll
      for (int i = 0; i < 8; i++) {
        ushort_t h = bf16_rne(vv[i]);
        dAh[idxA[i]] = h;
        dAl[idxA[i]] = bf16_rne(vv[i] - bf16f(h));
      }
    }
  }

  float bia[4];
  #pragma unroll
  for (int ci = 0; ci < 4; ci++) bia[ci] = in_b[wc*64 + ci*16 + ml];

  #pragma unroll
  for (int ri = 0; ri < 4; ri++) {
    #pragma unroll
    for (int reg = 0; reg < 4; reg++) {
      float p = 0.f;
      #pragma unroll
      for (int ci = 0; ci < 4; ci++) {
        float v = acc[ri][ci][reg] + bia[ci];
        acc[ri][ci][reg] = v;
        p += v*v;
      }
      #pragma unroll
      for (int off = 1; off < 16; off <<= 1) p += __shfl_xor(p, off);
      if (ml == 0) e2s[wr*64 + ri*16 + quad*4 + reg][wc] = p;
    }
  }
  __syncthreads();
  if (tid < 128) {
    float s = ((e2s[tid][0] + e2s[tid][1]) + e2s[tid][2]) + e2s[tid][3];
    float iv = 1.f / fmaxf(sqrtf(s), EPSF);
    sIv[tid] = iv;
    inv[r0 + tid]   = iv;
    enc2[r0 + tid]  = (s * iv) * iv;
    e2raw[r0 + tid] = s;
  }
  __syncthreads();

  ushort_t* tb = smem;
  #pragma unroll
  for (int ri = 0; ri < 4; ri++) {
    #pragma unroll
    for (int reg = 0; reg < 4; reg++) {
      int t_loc = wr*64 + ri*16 + quad*4 + reg;
      float ivt = sIv[t_loc];
      #pragma unroll
      for (int ci = 0; ci < 4; ci++) {
        int c_loc = wc*64 + ci*16 + ml;
        tb[t_loc*256 + c_loc] = bf16_rne(acc[ri][ci][reg] * ivt);
      }
    }
  }
  __syncthreads();
  #pragma unroll
  for (int p = 0; p < 8; p++) {
    int ch = p*512 + tid;
    *(short8*)(ehi + r0*DC + (size_t)ch*8) = *(const short8*)(tb + ch*8);
  }
  __syncthreads();
  #pragma unroll
  for (int ri = 0; ri < 4; ri++) {
    #pragma unroll
    for (int reg = 0; reg < 4; reg++) {
      int t_loc = wr*64 + ri*16 + quad*4 + reg;
      float ivt = sIv[t_loc];
      #pragma unroll
      for (int ci = 0; ci < 4; ci++) {
        int c_loc = wc*64 + ci*16 + ml;
        float v = acc[ri][ci][reg] * ivt;
        ushort_t h = bf16_rne(v);
        tb[t_loc*256 + c_loc] = bf16_rne(v - bf16f(h));
      }
    }
  }
  __syncthreads();
  #pragma unroll
  for (int p = 0; p < 8; p++) {
    int ch = p*512 + tid;
    *(short8*)(elo + r0*DC + (size_t)ch*8) = *(const short8*)(tb + ch*8);
  }
}

// ---------------- fused distance+argmin | W2T GEMM ----------------
// grid 4608 x 512: blocks [0,4096) run the R3-proven dist body
// (j0=(bid&31)*256, r0=(bid>>5)*256 — same linear order as the old 2D grid);
// blocks [4096,4608) run the W2T GEMM (waves 0-3 active, waves 4-7 idle at
// barriers) reusing the dist LDS arrays. Appending W2T here removes a launch
// and lets its 512 blocks fill the dispatch tail.
__global__ __launch_bounds__(512, 2) void k_dist_mfma(
    const ushort_t* __restrict__ ehi, const ushort_t* __restrict__ elo,
    const ushort_t* __restrict__ cbh, const ushort_t* __restrict__ cbl,
    const float* __restrict__ nrm2, const float* __restrict__ enc2,
    unsigned long long* __restrict__ keys,
    const ushort_t* __restrict__ crh, const ushort_t* __restrict__ crl,
    const ushort_t* __restrict__ wouth, const ushort_t* __restrict__ woutl,
    float* __restrict__ W2T)
{
  __shared__ ushort_t sAh[2][8192];
  __shared__ ushort_t sAl[2][8192];
  __shared__ ushort_t sBh[2][8192];
  __shared__ ushort_t sBl[2][8192];
  __shared__ float sE2[256], sN2[256];
  __shared__ unsigned long long rkey[256];

  const int tid = threadIdx.x;
  const int lane = tid & 63;
  const int wave = tid >> 6;
  const int ml = lane & 15, quad = lane >> 4;

  if (blockIdx.x < 4096) {
    // ================= dist body (R3-proven, unchanged) =================
    const int bid = blockIdx.x;
    const int j0 = (bid & 31) * 256;
    const size_t r0 = (size_t)(bid >> 5) * 256;
    const int wr = wave >> 2, wc = wave & 3;

    if (tid < 256) {
      sE2[tid] = enc2[r0 + tid];
      sN2[tid] = nrm2[j0 + tid];
      rkey[tid] = 0xFFFFFFFFFFFFFFFFull;
    }

    const ushort_t* gAh = ehi + r0 * DC;
    const ushort_t* gAl = elo + r0 * DC;
    const ushort_t* gBh = cbh + (size_t)j0 * DC;
    const ushort_t* gBl = cbl + (size_t)j0 * DC;

    int goS[2];
    #pragma unroll
    for (int l = 0; l < 2; l++) {
      int chunk = l*512 + tid;
      int r = chunk >> 2, c = chunk & 3;
      int g = c ^ swz4(r);
      goS[l] = r*DC + (g << 3);
    }
    const int wu = wave * 512;

    int offA[8], offB[4];
    #pragma unroll
    for (int i = 0; i < 8; i++) {
      int r = wr*128 + i*16 + ml;
      int p = quad ^ swz4(r);
      offA[i] = r*64 + p*16;
    }
    #pragma unroll
    for (int i = 0; i < 4; i++) {
      int r = wc*64 + i*16 + ml;
      int p = quad ^ swz4(r);
      offB[i] = r*64 + p*16;
    }

    f32x4 acc[8][4];
    #pragma unroll
    for (int i = 0; i < 8; i++)
      #pragma unroll
      for (int j = 0; j < 4; j++) acc[i][j] = (f32x4)0.f;

    stage2(gBh,      &sBh[0][0], goS, wu);
    stage2(gBl,      &sBl[0][0], goS, wu);
    stage2(gAh,      &sAh[0][0], goS, wu);
    stage2(gAl,      &sAl[0][0], goS, wu);
    stage2(gBh + 32, &sBh[1][0], goS, wu);
    stage2(gBl + 32, &sBl[1][0], goS, wu);
    asm volatile("s_waitcnt vmcnt(4)" ::: "memory");
    asm volatile("s_waitcnt lgkmcnt(0)" ::: "memory");
    __builtin_amdgcn_s_barrier();
    __builtin_amdgcn_sched_barrier(0);

    short8 fa_h[4], fa_l[4], fb_h[4], fb_l[4];

    #pragma unroll 2
    for (int k = 0; k < 8; k++) {
      const int cb = k & 1, nb = cb ^ 1;
      const char* pAh = (const char*)&sAh[cb][0];
      const char* pAl = (const char*)&sAl[cb][0];
      const char* pBh = (const char*)&sBh[cb][0];
      const char* pBl = (const char*)&sBl[cb][0];
      __builtin_amdgcn_sched_barrier(0);

      #pragma unroll
      for (int i = 0; i < 4; i++) { fa_h[i] = LD8(pAh, offA[i]); fa_l[i] = LD8(pAl, offA[i]); }
      #pragma unroll
      for (int i = 0; i < 2; i++) { fb_h[i] = LD8(pBh, offB[i]); fb_l[i] = LD8(pBl, offB[i]); }
      if (k < 7) stage2(gAh + (size_t)(k+1)*32, &sAh[nb][0], goS, wu);
      __builtin_amdgcn_s_barrier();
      __builtin_amdgcn_s_setprio(1);
      qmfma<0, 0>(acc, fa_h, fa_l, fb_h, fb_l);
      __builtin_amdgcn_s_setprio(0);
      __builtin_amdgcn_s_barrier();

      #pragma unroll
      for (int i = 2; i < 4; i++) { fb_h[i] = LD8(pBh, offB[i]); fb_l[i] = LD8(pBl, offB[i]); }
      if (k < 7) stage2(gAl + (size_t)(k+1)*32, &sAl[nb][0], goS, wu);
      __builtin_amdgcn_s_barrier();
      __builtin_amdgcn_s_setprio(1);
      qmfma<0, 2>(acc, fa_h, fa_l, fb_h, fb_l);
      __builtin_amdgcn_s_setprio(0);
      __builtin_amdgcn_s_barrier();

      #pragma unroll
      for (int i = 0; i < 4; i++) { fa_h[i] = LD8(pAh, offA[4+i]); fa_l[i] = LD8(pAl, offA[4+i]); }
      if (k < 6) {
        stage2(gBh + (size_t)(k+2)*32, &sBh[cb][0], goS, wu);
        stage2(gBl + (size_t)(k+2)*32, &sBl[cb][0], goS, wu);
      }
      __builtin_amdgcn_s_barrier();
      __builtin_amdgcn_s_setprio(1);
      qmfma<1, 2>(acc, fa_h, fa_l, fb_h, fb_l);
      qmfma<1, 0>(acc, fa_h, fa_l, fb_h, fb_l);
      __builtin_amdgcn_s_setprio(0);
      if (k < 6) { asm volatile("s_waitcnt vmcnt(4)" ::: "memory"); }
      else       { asm volatile("s_waitcnt vmcnt(0)" ::: "memory"); }
      __builtin_amdgcn_s_barrier();
    }

    #pragma unroll
    for (int ri = 0; ri < 8; ri++) {
      #pragma unroll
      for (int reg = 0; reg < 4; reg++) {
        int t_loc = wr*128 + ri*16 + quad*4 + reg;
        float e2 = sE2[t_loc];
        unsigned long long best = 0xFFFFFFFFFFFFFFFFull;
        #pragma unroll
        for (int ci = 0; ci < 4; ci++) {
          int j_loc = wc*64 + ci*16 + ml;
          float d = e2 - 2.0f * acc[ri][ci][reg];
          d = d + sN2[j_loc];
          unsigned long long key =
              ((unsigned long long)__float_as_uint(d) << 32) | (unsigned)(j0 + j_loc);
          best = key < best ? key : best;
        }
        #pragma unroll
        for (int off = 1; off < 16; off <<= 1) {
          unsigned long long o = __shfl_xor(best, off);
          best = o < best ? o : best;
        }
        if (ml == 0) atomicMin(&rkey[t_loc], best);
      }
    }
    __syncthreads();
    if (tid < 256) atomicMin(&keys[r0 + tid], rkey[tid]);
  } else {
    // ================= W2T body (waves 0-3 active) =================
    const int id = blockIdx.x - 4096;
    const int m0 = (id & 63) * 128;
    const int n0 = (id >> 6) * 128;
    const bool act = tid < 256;
    const int wr = (wave & 3) >> 1, wc = wave & 1;
    const int rr = lane >> 2, cc = lane & 3;

    const ushort_t* src = crh; ushort_t* dst = &sAh[0][0];
    {
      size_t aoff = (size_t)m0 * DC;
      size_t boff = (size_t)n0 * DC;
      if      (wave == 0) { src = crh + aoff;   dst = &sAh[0][0]; }
      else if (wave == 1) { src = crl + aoff;   dst = &sAl[0][0]; }
      else if (wave == 2) { src = wouth + boff; dst = &sBh[0][0]; }
      else if (wave == 3) { src = woutl + boff; dst = &sBl[0][0]; }
    }

    int goT[8];
    #pragma unroll
    for (int i = 0; i < 8; i++) {
      int r = i*16 + rr;
      int g = cc ^ swz4(r);
      goT[i] = r*DC + (g << 3);
    }

    int offA[4], offB[4];
    #pragma unroll
    for (int ri = 0; ri < 4; ri++) {
      int r = wr*64 + ri*16 + ml;
      int p = quad ^ swz4(r);
      offA[ri] = r*64 + p*16;
    }
    #pragma unroll
    for (int ci = 0; ci < 4; ci++) {
      int r = wc*64 + ci*16 + ml;
      int p = quad ^ swz4(r);
      offB[ci] = r*64 + p*16;
    }

    f32x4 acc[4][4];
    #pragma unroll
    for (int i = 0; i < 4; i++)
      #pragma unroll
      for (int j = 0; j < 4; j++) acc[i][j] = (f32x4)0.f;

    if (act) stage_tile8(src, dst, goT);

    for (int it = 0; it < 8; ++it) {
      __syncthreads();
      if (act && it < 7) stage_tile8(src + (it+1)*32, dst + ((it+1)&1)*4096, goT);
      const int bo = (it & 1) << 13;
      if (act) {
        short8 bh[4], bl[4];
        #pragma unroll
        for (int ci = 0; ci < 4; ci++) {
          bh[ci] = *(const short8*)((const char*)&sBh[0][0] + bo + offB[ci]);
          bl[ci] = *(const short8*)((const char*)&sBl[0][0] + bo + offB[ci]);
        }
        #pragma unroll
        for (int ri = 0; ri < 4; ri++) {
          short8 ah = *(const short8*)((const char*)&sAh[0][0] + bo + offA[ri]);
          short8 al = *(const short8*)((const char*)&sAl[0][0] + bo + offA[ri]);
          #pragma unroll
          for (int ci = 0; ci < 4; ci++) {
            acc[ri][ci] = __builtin_amdgcn_mfma_f32_16x16x32_bf16(ah, bh[ci], acc[ri][ci], 0, 0, 0);
            acc[ri][ci] = __builtin_amdgcn_mfma_f32_16x16x32_bf16(al, bh[ci], acc[ri][ci], 0, 0, 0);
            acc[ri][ci] = __builtin_amdgcn_mfma_f32_16x16x32_bf16(ah, bl[ci], acc[ri][ci], 0, 0, 0);
          }
        }
      }
    }

    if (act) {
      #pragma unroll
      for (int ri = 0; ri < 4; ri++) {
        int m_loc = wr*64 + ri*16 + quad*4;
        #pragma unroll
        for (int ci = 0; ci < 4; ci++) {
          int n_loc = wc*64 + ci*16 + ml;
          #pragma unroll
          for (int reg = 0; reg < 4; reg++) {
            W2T[(size_t)(m0 + m_loc + reg)*DIN + n0 + n_loc] = acc[ri][ci][reg];
          }
        }
      }
    }
  }
}

// ---------------- fallback-only: column norms + enc split + loss ----------------
__global__ void k_colnorm(const float* __restrict__ ze, float* __restrict__ inv,
                          float* __restrict__ enc2) {
  int r = blockIdx.x * 128 + threadIdx.x;
  int b = r >> 12, t = r & 4095;
  const float* p = ze + (size_t)b*DC*TT + t;
  float s = 0.f;
  for (int c = 0; c < DC; c++) { float x = p[(size_t)c*TT]; s += x*x; }
  float iv = 1.f / fmaxf(sqrtf(s), EPSF);
  inv[r] = iv;
  enc2[r] = (s * iv) * iv;
}

__global__ void k_split_enc(const float* __restrict__ ze, const float* __restrict__ inv,
                            ushort_t* __restrict__ ehi, ushort_t* __restrict__ elo) {
  __shared__ float tile[64][65];
  int b = blockIdx.z, t0 = blockIdx.x * 64, c0 = blockIdx.y * 64;
  int tx = threadIdx.x & 63, ty = threadIdx.x >> 6;
  const float* zb = ze + (size_t)b*DC*TT;
  #pragma unroll
  for (int i = 0; i < 16; i++) {
    int c = i*4 + ty;
    tile[c][tx] = zb[(size_t)(c0+c)*TT + t0 + tx];
  }
  __syncthreads();
  #pragma unroll
  for (int i = 0; i < 16; i++) {
    int t = i*4 + ty;
    float iv = inv[b*TT + t0 + t];
    float val = tile[tx][t] * iv;
    ushort_t h = bf16_rne(val);
    size_t o = ((size_t)(b*TT + t0 + t))*DC + c0 + tx;
    ehi[o] = h;
    elo[o] = bf16_rne(val - bf16f(h));
  }
}

__global__ void k_lossidx(const float* __restrict__ ze, const float* __restrict__ cb,
                          const unsigned long long* __restrict__ keys,
                          float* __restrict__ loss_sums, float* __restrict__ out_idx)
{
  __shared__ float sb[4];
  __shared__ int sj[64];
  int b = blockIdx.y, t0 = blockIdx.x * 64;
  int tid = threadIdx.x;
  if (tid < 64) {
    unsigned long long k = keys[(size_t)b*TT + t0 + tid];
    int j = (int)(unsigned)(k & 0xFFFFFFFFull);
    sj[tid] = j;
    out_idx[(size_t)b*TT + t0 + tid] = (float)j;
  }
  __syncthreads();
  int tt = tid & 63, tc = tid >> 6;
  const float* zb = ze + (size_t)b*DC*TT + t0;
  int j = sj[tt];
  float s = 0.f;
  for (int ci = 0; ci < 64; ci++) {
    int c = tc + ci*4;
    float zev = zb[(size_t)c*TT + tt];
    float zqv = cb[(size_t)j*DC + c];
    float d = zev - zqv;
    s += d*d;
  }
  s = block_reduce_sum_256(s, sb);
  if (tid == 0) atomicAdd(&loss_sums[b], s);
}

// ---------------- old dist (fallback path) ----------------
__global__ __launch_bounds__(512, 2) void k_dist_fb(
    const ushort_t* __restrict__ ehi, const ushort_t* __restrict__ elo,
    const ushort_t* __restrict__ cbh, const ushort_t* __restrict__ cbl,
    const float* __restrict__ nrm2, const float* __restrict__ enc2,
    unsigned long long* __restrict__ keys)
{
  __shared__ ushort_t sAh[2][8192];
  __shared__ ushort_t sAl[2][8192];
  __shared__ ushort_t sBh[2][8192];
  __shared__ ushort_t sBl[2][8192];
  __shared__ float sE2[256], sN2[256];
  __shared__ unsigned long long rkey[256];

  const int j0 = blockIdx.x * 256;
  const size_t r0 = (size_t)blockIdx.y * 256;
  const int tid = threadIdx.x;
  const int lane = tid & 63;
  const int wave = tid >> 6;
  const int wr = wave >> 2, wc = wave & 3;
  const int ml = lane & 15, quad = lane >> 4;

  if (tid < 256) {
    sE2[tid] = enc2[r0 + tid];
    sN2[tid] = nrm2[j0 + tid];
    rkey[tid] = 0xFFFFFFFFFFFFFFFFull;
  }

  const ushort_t* gAh = ehi + r0 * DC;
  const ushort_t* gAl = elo + r0 * DC;
  const ushort_t* gBh = cbh + (size_t)j0 * DC;
  const ushort_t* gBl = cbl + (size_t)j0 * DC;

  int goS[2];
  #pragma unroll
  for (int l = 0; l < 2; l++) {
    int chunk = l*512 + tid;
    int r = chunk >> 2, c = chunk & 3;
    int g = c ^ swz4(r);
    goS[l] = r*DC + (g << 3);
  }
  const int wu = wave * 512;

  int offA[8], offB[4];
  #pragma unroll
  for (int i = 0; i < 8; i++) {
    int r = wr*128 + i*16 + ml;
    int p = quad ^ swz4(r);
    offA[i] = r*64 + p*16;
  }
  #pragma unroll
  for (int i = 0; i < 4; i++) {
    int r = wc*64 + i*16 + ml;
    int p = quad ^ swz4(r);
    offB[i] = r*64 + p*16;
  }

  f32x4 acc[8][4];
  #pragma unroll
  for (int i = 0; i < 8; i++)
    #pragma unroll
    for (int j = 0; j < 4; j++) acc[i][j] = (f32x4)0.f;

  stage2(gBh,      &sBh[0][0], goS, wu);
  stage2(gBl,      &sBl[0][0], goS, wu);
  stage2(gAh,      &sAh[0][0], goS, wu);
  stage2(gAl,      &sAl[0][0], goS, wu);
  stage2(gBh + 32, &sBh[1][0], goS, wu);
  stage2(gBl + 32, &sBl[1][0], goS, wu);
  asm volatile("s_waitcnt vmcnt(4)" ::: "memory");
  asm volatile("s_waitcnt lgkmcnt(0)" ::: "memory");
  __builtin_amdgcn_s_barrier();
  __builtin_amdgcn_sched_barrier(0);

  short8 fa_h[4], fa_l[4], fb_h[4], fb_l[4];

  #pragma unroll 2
  for (int k = 0; k < 8; k++) {
    const int cb = k & 1, nb = cb ^ 1;
    const char* pAh = (const char*)&sAh[cb][0];
    const char* pAl = (const char*)&sAl[cb][0];
    const char* pBh = (const char*)&sBh[cb][0];
    const char* pBl = (const char*)&sBl[cb][0];
    __builtin_amdgcn_sched_barrier(0);

    #pragma unroll
    for (int i = 0; i < 4; i++) { fa_h[i] = LD8(pAh, offA[i]); fa_l[i] = LD8(pAl, offA[i]); }
    #pragma unroll
    for (int i = 0; i < 2; i++) { fb_h[i] = LD8(pBh, offB[i]); fb_l[i] = LD8(pBl, offB[i]); }
    if (k < 7) stage2(gAh + (size_t)(k+1)*32, &sAh[nb][0], goS, wu);
    __builtin_amdgcn_s_barrier();
    __builtin_amdgcn_s_setprio(1);
    qmfma<0, 0>(acc, fa_h, fa_l, fb_h, fb_l);
    __builtin_amdgcn_s_setprio(0);
    __builtin_amdgcn_s_barrier();

    #pragma unroll
    for (int i = 2; i < 4; i++) { fb_h[i] = LD8(pBh, offB[i]); fb_l[i] = LD8(pBl, offB[i]); }
    if (k < 7) stage2(gAl + (size_t)(k+1)*32, &sAl[nb][0], goS, wu);
    __builtin_amdgcn_s_barrier();
    __builtin_amdgcn_s_setprio(1);
    qmfma<0, 2>(acc, fa_h, fa_l, fb_h, fb_l);
    __builtin_amdgcn_s_setprio(0);
    __builtin_amdgcn_s_barrier();

    #pragma unroll
    for (int i = 0; i < 4; i++) { fa_h[i] = LD8(pAh, offA[4+i]); fa_l[i] = LD8(pAl, offA[4+i]); }
    if (k < 6) {
      stage2(gBh + (size_t)(k+2)*32, &sBh[cb][0], goS, wu);
      stage2(gBl + (size_t)(k+2)*32, &sBl[cb][0], goS, wu);
    }
    __builtin_amdgcn_s_barrier();
    __builtin_amdgcn_s_setprio(1);
    qmfma<1, 2>(acc, fa_h, fa_l, fb_h, fb_l);
    qmfma<1, 0>(acc, fa_h, fa_l, fb_h, fb_l);
    __builtin_amdgcn_s_setprio(0);
    if (k < 6) { asm volatile("s_waitcnt vmcnt(4)" ::: "memory"); }
    else       { asm volatile("s_waitcnt vmcnt(0)" ::: "memory"); }
    __builtin_amdgcn_s_barrier();
  }

  #pragma unroll
  for (int ri = 0; ri < 8; ri++) {
    #pragma unroll
    for (int reg = 0; reg < 4; reg++) {
      int t_loc = wr*128 + ri*16 + quad*4 + reg;
      float e2 = sE2[t_loc];
      unsigned long long best = 0xFFFFFFFFFFFFFFFFull;
      #pragma unroll
      for (int ci = 0; ci < 4; ci++) {
        int j_loc = wc*64 + ci*16 + ml;
        float d = e2 - 2.0f * acc[ri][ci][reg];
        d = d + sN2[j_loc];
        unsigned long long key =
            ((unsigned long long)__float_as_uint(d) << 32) | (unsigned)(j0 + j_loc);
        best = key < best ? key : best;
      }
      #pragma unroll
      for (int off = 1; off < 16; off <<= 1) {
        unsigned long long o = __shfl_xor(best, off);
        best = o < best ? o : best;
      }
      if (ml == 0) atomicMin(&rkey[t_loc], best);
    }
  }
  __syncthreads();
  if (tid < 256) atomicMin(&keys[r0 + tid], rkey[tid]);
}

__global__ void k_losswrite(const float* __restrict__ loss_sums, float* __restrict__ out_loss) {
  int i = threadIdx.x;
  if (i < 8) {
    float v = loss_sums[i] * (1.f/1048576.f);
    out_loss[i] = v;
    out_loss[8 + i] = v;
  }
}

// ---------------- output gather (+ optional fused loss/idx) ----------------
// WITH_LOSS: folds the per-row loss reconstruction + out_idx write into the
// first phase (tid<64 = wave 0 handles the block's 64 rows; wave-reduce ->
// one atomicAdd). Gather phases use float4 global load/store; LDS tile kept
// [64][65] with scalar LDS accesses (<=2-way banks, verified).
template<bool WITH_LOSS>
__global__ void k_outgather(const float* __restrict__ W2T,
                            const unsigned long long* __restrict__ keys,
                            const float* __restrict__ out_b, float* __restrict__ out,
                            const float* __restrict__ enc2, const float* __restrict__ nrm2,
                            const float* __restrict__ e2raw, const float* __restrict__ inv,
                            const float* __restrict__ nmraw, const float* __restrict__ n2raw,
                            float* __restrict__ loss_sums, float* __restrict__ out_idx)
{
  __shared__ float tile[64][65];
  __shared__ int sj[64];
  int b = blockIdx.y, t0 = blockIdx.x * 64;
  int tid = threadIdx.x;
  if (tid < 64) {
    size_t r = (size_t)b*TT + t0 + tid;
    unsigned long long k = keys[r];
    int j = (int)(unsigned)(k & 0xFFFFFFFFull);
    sj[tid] = j;
    if (WITH_LOSS) {
      out_idx[r] = (float)j;
      float d = __uint_as_float((unsigned)(k >> 32));
      float dotn = 0.5f * (enc2[r] + nrm2[j] - d);
      float dot_raw = nmraw[j] * dotn / inv[r];
      float le = e2raw[r] - 2.f*dot_raw + n2raw[j];
      #pragma unroll
      for (int o = 32; o > 0; o >>= 1) le += __shfl_down(le, o, 64);
      if (tid == 0) atomicAdd(&loss_sums[b], le);
    }
  }
  __syncthreads();
  float* ob = out + (size_t)b*DIN*TT;
  const int tg = tid >> 4;          // 0..15
  const int d4 = (tid & 15) * 4;    // 0..60 step 4
  const int t4 = tid & 15;          // 0..15
  const int dq = tid >> 4;          // 0..15
  for (int d0 = 0; d0 < DIN; d0 += 64) {
    #pragma unroll
    for (int i = 0; i < 4; i++) {
      int t = i*16 + tg;
      float4 v = *(const float4*)&W2T[(size_t)sj[t]*DIN + d0 + d4];
      tile[t][d4+0] = v.x; tile[t][d4+1] = v.y;
      tile[t][d4+2] = v.z; tile[t][d4+3] = v.w;
    }
    __syncthreads();
    #pragma unroll
    for (int i = 0; i < 4; i++) {
      int d = i*16 + dq;
      float bia = out_b[d0+d];
      float4 v = make_float4(tile[t4*4+0][d]+bia, tile[t4*4+1][d]+bia,
                             tile[t4*4+2][d]+bia, tile[t4*4+3][d]+bia);
      *(float4*)&ob[(size_t)(d0+d)*TT + t0 + t4*4] = v;
    }
    __syncthreads();
  }
}

// ---------------- launch ----------------
extern "C" void kernel_launch(void* const* d_in, const int* in_sizes, int n_in,
                              void* d_out, int out_size, void* d_ws, size_t ws_size,
                              hipStream_t stream) {
  const float* z        = (const float*)d_in[0];
  const float* in_v     = (const float*)d_in[1];
  const float* in_g     = (const float*)d_in[2];
  const float* in_b     = (const float*)d_in[3];
  const float* out_v    = (const float*)d_in[4];
  const float* out_g    = (const float*)d_in[5];
  const float* out_b    = (const float*)d_in[6];
  const float* codebook = (const float*)d_in[7];

  char* w = (char*)d_ws;
  float* w_in   = (float*)(w + OFF_WIN);
  float* w_outT = (float*)(w + OFF_WOUTT);               // fallback only
  float* e2raw  = (float*)(w + OFF_WOUTT);               // mfma only (aliases w_outT)
  float* nmraw  = (float*)(w + OFF_WOUTT + 131072);
  float* n2raw  = (float*)(w + OFF_WOUTT + 163840);
  ushort_t* cb_hi = (ushort_t*)(w + OFF_CBN);
  ushort_t* cb_lo = cb_hi + (size_t)CS*DC;
  float* nrm2   = (float*)(w + OFF_NRM2);
  float* z_e    = (float*)(w + OFF_ZE);                  // fallback only
  ushort_t* enc_hi_m = (ushort_t*)(w + OFF_ZE);          // mfma only (aliases z_e)
  ushort_t* enc_lo_m = enc_hi_m + (size_t)BB*TT*DC;
  float* inv    = (float*)(w + OFF_INV);
  float* enc2   = (float*)(w + OFF_ENC2);
  unsigned long long* keys = (unsigned long long*)(w + OFF_KEYS);
  float* loss_sums = (float*)(w + OFF_LOSS);
  ushort_t* w_hi = (ushort_t*)(w + OFF_WSPL);
  ushort_t* w_lo = w_hi + (size_t)DC*DIN;
  ushort_t* enc_hi_fb = (ushort_t*)(w + OFF_W2T);        // fallback enc location
  ushort_t* enc_lo_fb = enc_hi_fb + (size_t)BB*TT*DC;
  float* W2T    = (float*)(w + OFF_W2T);
  ushort_t* cbr_hi  = (ushort_t*)(w + OFF_W2T + 33554432);
  ushort_t* cbr_lo  = cbr_hi + (size_t)CS*DC;
  ushort_t* wout_hi = (ushort_t*)(w + OFF_W2T + 33554432 + 8388608);
  ushort_t* wout_lo = wout_hi + (size_t)DIN*DC;

  float* out      = (float*)d_out;
  float* out_loss = out + (size_t)BB*DIN*TT;
  float* out_idx  = out_loss + 16;

  const bool mfma_path = (ws_size >= REQ_WS_ZE);

  if (mfma_path) {
    // 5 dispatches total; keys/loss init folded into prep.
    k_prep_all<<<9472, 256, 0, stream>>>(
        in_v, in_g, w_in, w_hi, w_lo,
        out_v, out_g, wout_hi, wout_lo,
        codebook, cb_hi, cb_lo, nrm2, nmraw, n2raw, cbr_hi, cbr_lo,
        keys, loss_sums);

    k_ze_enc<<<dim3(32, 8), 512, 0, stream>>>(
        z, w_hi, w_lo, in_b, enc_hi_m, enc_lo_m, inv, enc2, e2raw);

    k_dist_mfma<<<4608, 512, 0, stream>>>(
        enc_hi_m, enc_lo_m, cb_hi, cb_lo, nrm2, enc2, keys,
        cbr_hi, cbr_lo, wout_hi, wout_lo, W2T);

    k_outgather<true><<<dim3(64, 8), 256, 0, stream>>>(
        W2T, keys, out_b, out,
        enc2, nrm2, e2raw, inv, nmraw, n2raw, loss_sums, out_idx);

    k_losswrite<<<1, 64, 0, stream>>>(loss_sums, out_loss);
  } else {
    hipMemsetAsync(keys, 0xFF, 32768ull*8, stream);
    hipMemsetAsync(loss_sums, 0, 32, stream);

    k_prep_win <<<256, 256, 0, stream>>>(in_v, in_g, w_in, w_hi, w_lo);
    k_prep_cb  <<<8192, 256, 0, stream>>>(codebook, cb_hi, cb_lo, nrm2, nmraw, n2raw,
                                          cbr_hi, cbr_lo);
    k_prep_wout<<<1024, 256, 0, stream>>>(out_v, out_g, w_outT);
    k_gemm<true><<<dim3(32, 2, 8), 256, 0, stream>>>(
        w_in, z, in_b, z_e, 1024, 1024, 4096, 4096,
        (size_t)DIN*TT, (size_t)DC*TT);
    k_colnorm<<<256, 128, 0, stream>>>(z_e, inv, enc2);
    k_split_enc<<<dim3(64, 4, 8), 256, 0, stream>>>(z_e, inv, enc_hi_fb, enc_lo_fb);

    k_dist_fb<<<dim3(32, 128), 512, 0, stream>>>(
        enc_hi_fb, enc_lo_fb, cb_hi, cb_lo, nrm2, enc2, keys);

    k_lossidx<<<dim3(64, 8), 256, 0, stream>>>(z_e, codebook, keys, loss_sums, out_idx);
    k_losswrite<<<1, 64, 0, stream>>>(loss_sums, out_loss);

    k_gemm<false><<<dim3(8, 64, 1), 256, 0, stream>>>(
        codebook, w_outT, nullptr, W2T, 256, 256, 1024, 1024,
        (size_t)0, (size_t)0);

    k_outgather<false><<<dim3(64, 8), 256, 0, stream>>>(
        W2T, keys, out_b, out,
        nullptr, nullptr, nullptr, nullptr, nullptr, nullptr, nullptr, nullptr);
  }
}